// Round 1
// baseline (428.094 us; speedup 1.0000x reference)
//
#include <hip/hip_runtime.h>

#define NN 50000
#define NE 800000

// ---------------- CSR build ----------------
__global__ void k_zero_cnt(int* __restrict__ cnt) {
  int i = blockIdx.x * blockDim.x + threadIdx.x;
  if (i < NN) cnt[i] = 0;
}

__global__ void k_hist(const int* __restrict__ dst, int* __restrict__ cnt) {
  int e = blockIdx.x * blockDim.x + threadIdx.x;
  if (e < NE) atomicAdd(&cnt[dst[e]], 1);
}

// single block, 1024 threads: exclusive scan of cnt -> off, cur; dinv = rsqrt(cnt+1)
__global__ void k_scan(const int* __restrict__ cnt, int* __restrict__ off,
                       int* __restrict__ cur, float* __restrict__ dinv) {
  __shared__ int part[1024];
  const int T = 1024;
  const int chunk = (NN + T - 1) / T;  // 49
  int t = threadIdx.x;
  int lo = t * chunk;
  int hi = min(lo + chunk, NN);
  int s = 0;
  for (int i = lo; i < hi; ++i) s += cnt[i];
  part[t] = s;
  __syncthreads();
  for (int d = 1; d < T; d <<= 1) {
    int v = (t >= d) ? part[t - d] : 0;
    __syncthreads();
    part[t] += v;
    __syncthreads();
  }
  int run = part[t] - s;  // exclusive prefix at this thread's chunk start
  for (int i = lo; i < hi; ++i) {
    int c = cnt[i];
    off[i] = run;
    cur[i] = run;
    dinv[i] = rsqrtf((float)(c + 1));  // +1 self-loop; deg>=1 always
    run += c;
  }
  if (t == T - 1) off[NN] = part[T - 1];
}

__global__ void k_fill(const int* __restrict__ src, const int* __restrict__ dst,
                       int* __restrict__ cur, int* __restrict__ ssrc) {
  int e = blockIdx.x * blockDim.x + threadIdx.x;
  if (e < NE) {
    int p = atomicAdd(&cur[dst[e]], 1);
    ssrc[p] = src[e];
  }
}

// ---------------- dense GEMM: H[M x ND] = X[M x KD] @ W[KD x ND] ----------------
// block = 256 threads; each thread computes a float4 of outputs.
template <int KD, int ND, int RPI>
__global__ __launch_bounds__(256) void k_gemm(const float* __restrict__ X,
                                              const float* __restrict__ W,
                                              float* __restrict__ H, int ntiles) {
  __shared__ __attribute__((aligned(16))) float Wl[KD * ND];
  __shared__ __attribute__((aligned(16))) float xs[RPI * KD];
  for (int i = threadIdx.x; i < KD * ND / 4; i += 256)
    ((float4*)Wl)[i] = ((const float4*)W)[i];
  const int NQ = ND / 4;                // col-quads
  int q = threadIdx.x % NQ;
  int r = threadIdx.x / NQ;             // row within tile
  for (int tile = blockIdx.x; tile < ntiles; tile += gridDim.x) {
    __syncthreads();                    // Wl ready (1st iter) / xs readers done
    const float4* Xv = (const float4*)(X + (size_t)tile * RPI * KD);
    for (int i = threadIdx.x; i < RPI * KD / 4; i += 256)
      ((float4*)xs)[i] = Xv[i];
    __syncthreads();
    float4 acc = make_float4(0.f, 0.f, 0.f, 0.f);
    const float* xr = xs + r * KD;
#pragma unroll 8
    for (int k = 0; k < KD; ++k) {
      float xv = xr[k];
      float4 w = ((const float4*)Wl)[k * NQ + q];
      acc.x = fmaf(xv, w.x, acc.x);
      acc.y = fmaf(xv, w.y, acc.y);
      acc.z = fmaf(xv, w.z, acc.z);
      acc.w = fmaf(xv, w.w, acc.w);
    }
    ((float4*)H)[((size_t)tile * RPI + r) * NQ + q] = acc;
  }
}

// ---------------- gather aggregation: one wave per node ----------------
// out[n] = relu( bias + dinv[n]^2 * H[n] + sum_{edges s->n} dinv[s]*dinv[n]*H[s] )
template <int D>
__global__ __launch_bounds__(256) void k_agg(const float* __restrict__ H,
                                             const int* __restrict__ off,
                                             const int* __restrict__ ssrc,
                                             const float* __restrict__ dinv,
                                             const float* __restrict__ bias,
                                             float* __restrict__ out) {
  int gw = (blockIdx.x * 256 + threadIdx.x) >> 6;  // global wave id = node
  int lane = threadIdx.x & 63;
  if (gw >= NN) return;
  const int n = gw;
  float dn = dinv[n];
  int jb = off[n], je = off[n + 1];
  if constexpr (D == 128) {
    const float2* Hv = (const float2*)H;
    float2 acc;
    {
      float2 h = Hv[(size_t)n * 64 + lane];
      float w = dn * dn;
      acc.x = h.x * w;
      acc.y = h.y * w;
    }
    int j = jb;
    for (; j + 1 < je; j += 2) {
      int s0 = ssrc[j], s1 = ssrc[j + 1];
      float w0 = dinv[s0] * dn, w1 = dinv[s1] * dn;
      float2 h0 = Hv[(size_t)s0 * 64 + lane];
      float2 h1 = Hv[(size_t)s1 * 64 + lane];
      acc.x = fmaf(h0.x, w0, acc.x);
      acc.y = fmaf(h0.y, w0, acc.y);
      acc.x = fmaf(h1.x, w1, acc.x);
      acc.y = fmaf(h1.y, w1, acc.y);
    }
    if (j < je) {
      int s0 = ssrc[j];
      float w0 = dinv[s0] * dn;
      float2 h0 = Hv[(size_t)s0 * 64 + lane];
      acc.x = fmaf(h0.x, w0, acc.x);
      acc.y = fmaf(h0.y, w0, acc.y);
    }
    float2 b = ((const float2*)bias)[lane];
    acc.x = fmaxf(acc.x + b.x, 0.f);
    acc.y = fmaxf(acc.y + b.y, 0.f);
    ((float2*)out)[(size_t)n * 64 + lane] = acc;
  } else {  // D == 64
    float acc = H[(size_t)n * 64 + lane] * (dn * dn);
    int j = jb;
    for (; j + 1 < je; j += 2) {
      int s0 = ssrc[j], s1 = ssrc[j + 1];
      float w0 = dinv[s0] * dn, w1 = dinv[s1] * dn;
      float h0 = H[(size_t)s0 * 64 + lane];
      float h1 = H[(size_t)s1 * 64 + lane];
      acc = fmaf(h0, w0, acc);
      acc = fmaf(h1, w1, acc);
    }
    if (j < je) {
      int s0 = ssrc[j];
      float w0 = dinv[s0] * dn;
      acc = fmaf(H[(size_t)s0 * 64 + lane], w0, acc);
    }
    acc = fmaxf(acc + bias[lane], 0.f);
    out[(size_t)n * 64 + lane] = acc;
  }
}

extern "C" void kernel_launch(void* const* d_in, const int* in_sizes, int n_in,
                              void* d_out, int out_size, void* d_ws, size_t ws_size,
                              hipStream_t stream) {
  const float* x  = (const float*)d_in[0];
  const int*   ei = (const int*)d_in[1];
  const float* W1 = (const float*)d_in[2];
  const float* b1 = (const float*)d_in[3];
  const float* W2 = (const float*)d_in[4];
  const float* b2 = (const float*)d_in[5];
  const int* esrc = ei;
  const int* edst = ei + NE;

  char* ws = (char*)d_ws;
  int*   cnt  = (int*)(ws + 0);          // 200,000 B
  int*   off  = (int*)(ws + 200704);     // 200,004 B (NN+1)
  int*   cur  = (int*)(ws + 401408);     // 200,000 B
  int*   ssrc = (int*)(ws + 602112);     // 3,200,000 B
  float* dinv = (float*)(ws + 3802112);  // 200,000 B
  float* h1   = (float*)(ws + 4194304);  // 25,600,000 B (also reused for h3)
  float* agg1 = (float*)(ws + 29794304); // 25,600,000 B (h2 = relu(agg1+b1) in place)
  // total ws usage: ~55.4 MB

  hipLaunchKernelGGL(k_zero_cnt, dim3((NN + 255) / 256), dim3(256), 0, stream, cnt);
  hipLaunchKernelGGL(k_hist, dim3((NE + 255) / 256), dim3(256), 0, stream, edst, cnt);
  hipLaunchKernelGGL(k_scan, dim3(1), dim3(1024), 0, stream, cnt, off, cur, dinv);
  hipLaunchKernelGGL(k_fill, dim3((NE + 255) / 256), dim3(256), 0, stream, esrc, edst, cur, ssrc);

  // layer 1: h1 = x @ W1 ; agg1 = relu(A_norm h1 + b1)
  hipLaunchKernelGGL((k_gemm<128, 128, 8>), dim3(1024), dim3(256), 0, stream, x, W1, h1, NN / 8);
  hipLaunchKernelGGL((k_agg<128>), dim3(NN / 4), dim3(256), 0, stream, h1, off, ssrc, dinv, b1, agg1);

  // layer 2: h3 = agg1 @ W2 (into h1 buffer) ; d_out = relu(A_norm h3 + b2)
  hipLaunchKernelGGL((k_gemm<128, 64, 16>), dim3(1024), dim3(256), 0, stream, agg1, W2, h1, NN / 16);
  hipLaunchKernelGGL((k_agg<64>), dim3(NN / 4), dim3(256), 0, stream, h1, off, ssrc, dinv, b2, (float*)d_out);
}

// Round 2
// 274.679 us; speedup vs baseline: 1.5585x; 1.5585x over previous
//
#include <hip/hip_runtime.h>

#define NN 50000
#define NE 800000
#define SCHUNK 1024
#define NSB ((NN + SCHUNK - 1) / SCHUNK)  // 49

// ---------------- CSR build ----------------
__global__ void k_hist(const int* __restrict__ dst, int* __restrict__ cnt) {
  int e = blockIdx.x * blockDim.x + threadIdx.x;
  if (e < NE) atomicAdd(&cnt[dst[e]], 1);
}

// Pass 1: per-block (1024-elem) partial sums of cnt
__global__ __launch_bounds__(256) void k_psum(const int* __restrict__ cnt,
                                              int* __restrict__ bsum) {
  int t = threadIdx.x;
  int i0 = blockIdx.x * SCHUNK + t * 4;
  int s = 0;
#pragma unroll
  for (int k = 0; k < 4; ++k)
    if (i0 + k < NN) s += cnt[i0 + k];
  // wave reduce
#pragma unroll
  for (int d = 32; d >= 1; d >>= 1) s += __shfl_down(s, d);
  __shared__ int wsum[4];
  int lane = t & 63, w = t >> 6;
  if (lane == 0) wsum[w] = s;
  __syncthreads();
  if (t == 0) bsum[blockIdx.x] = wsum[0] + wsum[1] + wsum[2] + wsum[3];
}

// Pass 2: single wave scans the NSB block sums -> bbase (exclusive), off[NN]=total
__global__ void k_bscan(const int* __restrict__ bsum, int* __restrict__ bbase,
                        int* __restrict__ off) {
  int t = threadIdx.x;  // 64 threads
  int v = (t < NSB) ? bsum[t] : 0;
  int incl = v;
#pragma unroll
  for (int d = 1; d < 64; d <<= 1) {
    int u = __shfl_up(incl, d);
    if (t >= d) incl += u;
  }
  if (t < NSB) bbase[t] = incl - v;
  if (t == 63) off[NN] = incl;  // total (== NE)
}

// Pass 3: per-block local exclusive scan + bbase -> off, cur, dinv
__global__ __launch_bounds__(256) void k_final(const int* __restrict__ cnt,
                                               const int* __restrict__ bbase,
                                               int* __restrict__ off,
                                               int* __restrict__ cur,
                                               float* __restrict__ dinv) {
  int t = threadIdx.x;
  int lane = t & 63, w = t >> 6;
  int i0 = blockIdx.x * SCHUNK + t * 4;
  int c[4];
  int s = 0;
#pragma unroll
  for (int k = 0; k < 4; ++k) {
    c[k] = (i0 + k < NN) ? cnt[i0 + k] : 0;
    s += c[k];
  }
  int incl = s;
#pragma unroll
  for (int d = 1; d < 64; d <<= 1) {
    int u = __shfl_up(incl, d);
    if (lane >= d) incl += u;
  }
  __shared__ int wsum[4];
  if (lane == 63) wsum[w] = incl;
  __syncthreads();
  int wbase = 0;
  for (int j = 0; j < w; ++j) wbase += wsum[j];
  int run = bbase[blockIdx.x] + wbase + (incl - s);
#pragma unroll
  for (int k = 0; k < 4; ++k) {
    if (i0 + k < NN) {
      off[i0 + k] = run;
      cur[i0 + k] = run;
      dinv[i0 + k] = rsqrtf((float)(c[k] + 1));
      run += c[k];
    }
  }
}

__global__ void k_fill(const int* __restrict__ src, const int* __restrict__ dst,
                       int* __restrict__ cur, int* __restrict__ ssrc) {
  int e = blockIdx.x * blockDim.x + threadIdx.x;
  if (e < NE) {
    int p = atomicAdd(&cur[dst[e]], 1);
    ssrc[p] = src[e];
  }
}

// ---------------- dense GEMM: H[M x ND] = X[M x KD] @ W[KD x ND] ----------------
template <int KD, int ND, int RPI>
__global__ __launch_bounds__(256) void k_gemm(const float* __restrict__ X,
                                              const float* __restrict__ W,
                                              float* __restrict__ H, int ntiles) {
  __shared__ __attribute__((aligned(16))) float Wl[KD * ND];
  __shared__ __attribute__((aligned(16))) float xs[RPI * KD];
  for (int i = threadIdx.x; i < KD * ND / 4; i += 256)
    ((float4*)Wl)[i] = ((const float4*)W)[i];
  const int NQ = ND / 4;  // col-quads
  int q = threadIdx.x % NQ;
  int r = threadIdx.x / NQ;  // row within tile
  for (int tile = blockIdx.x; tile < ntiles; tile += gridDim.x) {
    __syncthreads();  // Wl ready (1st iter) / xs readers done
    const float4* Xv = (const float4*)(X + (size_t)tile * RPI * KD);
    for (int i = threadIdx.x; i < RPI * KD / 4; i += 256)
      ((float4*)xs)[i] = Xv[i];
    __syncthreads();
    float4 acc = make_float4(0.f, 0.f, 0.f, 0.f);
    const float* xr = xs + r * KD;
#pragma unroll 8
    for (int k = 0; k < KD; ++k) {
      float xv = xr[k];
      float4 w = ((const float4*)Wl)[k * NQ + q];
      acc.x = fmaf(xv, w.x, acc.x);
      acc.y = fmaf(xv, w.y, acc.y);
      acc.z = fmaf(xv, w.z, acc.z);
      acc.w = fmaf(xv, w.w, acc.w);
    }
    ((float4*)H)[((size_t)tile * RPI + r) * NQ + q] = acc;
  }
}

// ---------------- gather aggregation: one wave per node ----------------
// out[n] = relu( bias + dinv[n]^2 * H[n] + sum_{edges s->n} dinv[s]*dinv[n]*H[s] )
template <int D>
__global__ __launch_bounds__(256) void k_agg(const float* __restrict__ H,
                                             const int* __restrict__ off,
                                             const int* __restrict__ ssrc,
                                             const float* __restrict__ dinv,
                                             const float* __restrict__ bias,
                                             float* __restrict__ out) {
  int gw = (blockIdx.x * 256 + threadIdx.x) >> 6;  // global wave id = node
  int lane = threadIdx.x & 63;
  if (gw >= NN) return;
  const int n = gw;
  float dn = dinv[n];
  int jb = off[n], je = off[n + 1];
  if constexpr (D == 128) {
    const float2* Hv = (const float2*)H;
    float2 acc;
    {
      float2 h = Hv[(size_t)n * 64 + lane];
      float w = dn * dn;
      acc.x = h.x * w;
      acc.y = h.y * w;
    }
    int j = jb;
    for (; j + 3 < je; j += 4) {
      int s0 = ssrc[j], s1 = ssrc[j + 1], s2 = ssrc[j + 2], s3 = ssrc[j + 3];
      float w0 = dinv[s0] * dn, w1 = dinv[s1] * dn;
      float w2 = dinv[s2] * dn, w3 = dinv[s3] * dn;
      float2 h0 = Hv[(size_t)s0 * 64 + lane];
      float2 h1 = Hv[(size_t)s1 * 64 + lane];
      float2 h2 = Hv[(size_t)s2 * 64 + lane];
      float2 h3 = Hv[(size_t)s3 * 64 + lane];
      acc.x = fmaf(h0.x, w0, acc.x); acc.y = fmaf(h0.y, w0, acc.y);
      acc.x = fmaf(h1.x, w1, acc.x); acc.y = fmaf(h1.y, w1, acc.y);
      acc.x = fmaf(h2.x, w2, acc.x); acc.y = fmaf(h2.y, w2, acc.y);
      acc.x = fmaf(h3.x, w3, acc.x); acc.y = fmaf(h3.y, w3, acc.y);
    }
    for (; j < je; ++j) {
      int s0 = ssrc[j];
      float w0 = dinv[s0] * dn;
      float2 h0 = Hv[(size_t)s0 * 64 + lane];
      acc.x = fmaf(h0.x, w0, acc.x); acc.y = fmaf(h0.y, w0, acc.y);
    }
    float2 b = ((const float2*)bias)[lane];
    acc.x = fmaxf(acc.x + b.x, 0.f);
    acc.y = fmaxf(acc.y + b.y, 0.f);
    ((float2*)out)[(size_t)n * 64 + lane] = acc;
  } else {  // D == 64
    float acc = H[(size_t)n * 64 + lane] * (dn * dn);
    int j = jb;
    for (; j + 3 < je; j += 4) {
      int s0 = ssrc[j], s1 = ssrc[j + 1], s2 = ssrc[j + 2], s3 = ssrc[j + 3];
      float w0 = dinv[s0] * dn, w1 = dinv[s1] * dn;
      float w2 = dinv[s2] * dn, w3 = dinv[s3] * dn;
      float h0 = H[(size_t)s0 * 64 + lane];
      float h1 = H[(size_t)s1 * 64 + lane];
      float h2 = H[(size_t)s2 * 64 + lane];
      float h3 = H[(size_t)s3 * 64 + lane];
      acc = fmaf(h0, w0, acc);
      acc = fmaf(h1, w1, acc);
      acc = fmaf(h2, w2, acc);
      acc = fmaf(h3, w3, acc);
    }
    for (; j < je; ++j) {
      int s0 = ssrc[j];
      acc = fmaf(H[(size_t)s0 * 64 + lane], dinv[s0] * dn, acc);
    }
    acc = fmaxf(acc + bias[lane], 0.f);
    out[(size_t)n * 64 + lane] = acc;
  }
}

extern "C" void kernel_launch(void* const* d_in, const int* in_sizes, int n_in,
                              void* d_out, int out_size, void* d_ws, size_t ws_size,
                              hipStream_t stream) {
  const float* x  = (const float*)d_in[0];
  const int*   ei = (const int*)d_in[1];
  const float* W1 = (const float*)d_in[2];
  const float* b1 = (const float*)d_in[3];
  const float* W2 = (const float*)d_in[4];
  const float* b2 = (const float*)d_in[5];
  const int* esrc = ei;
  const int* edst = ei + NE;

  char* ws = (char*)d_ws;
  int*   cnt  = (int*)(ws + 0);          // 200,000 B
  int*   off  = (int*)(ws + 200704);     // 200,004 B (NN+1)
  int*   cur  = (int*)(ws + 401408);     // 200,000 B
  int*   ssrc = (int*)(ws + 602112);     // 3,200,000 B
  float* dinv = (float*)(ws + 3802112);  // 200,000 B
  int*   bsum = (int*)(ws + 4002112);    // 196 B
  int*   bbase= (int*)(ws + 4003136);    // 196 B
  float* h1   = (float*)(ws + 4194304);  // 25,600,000 B (also reused for h3)
  float* agg1 = (float*)(ws + 29794304); // 25,600,000 B

  hipMemsetAsync(cnt, 0, NN * sizeof(int), stream);
  hipLaunchKernelGGL(k_hist, dim3((NE + 255) / 256), dim3(256), 0, stream, edst, cnt);
  hipLaunchKernelGGL(k_psum, dim3(NSB), dim3(256), 0, stream, cnt, bsum);
  hipLaunchKernelGGL(k_bscan, dim3(1), dim3(64), 0, stream, bsum, bbase, off);
  hipLaunchKernelGGL(k_final, dim3(NSB), dim3(256), 0, stream, cnt, bbase, off, cur, dinv);
  hipLaunchKernelGGL(k_fill, dim3((NE + 255) / 256), dim3(256), 0, stream, esrc, edst, cur, ssrc);

  // layer 1: h1 = x @ W1 ; agg1 = relu(A_norm h1 + b1)
  hipLaunchKernelGGL((k_gemm<128, 128, 8>), dim3(1024), dim3(256), 0, stream, x, W1, h1, NN / 8);
  hipLaunchKernelGGL((k_agg<128>), dim3(NN / 4), dim3(256), 0, stream, h1, off, ssrc, dinv, b1, agg1);

  // layer 2: h3 = agg1 @ W2 (into h1 buffer) ; d_out = relu(A_norm h3 + b2)
  hipLaunchKernelGGL((k_gemm<128, 64, 16>), dim3(1024), dim3(256), 0, stream, agg1, W2, h1, NN / 16);
  hipLaunchKernelGGL((k_agg<64>), dim3(NN / 4), dim3(256), 0, stream, h1, off, ssrc, dinv, b2, (float*)d_out);
}

// Round 3
// 261.010 us; speedup vs baseline: 1.6401x; 1.0524x over previous
//
#include <hip/hip_runtime.h>

#define NN 50000
#define NE 800000
#define SCHUNK 1024
#define NSB ((NN + SCHUNK - 1) / SCHUNK)  // 49

// ---------------- bf16 helpers (manual, RNE) ----------------
__device__ __forceinline__ unsigned f2bf(float f) {
  union { float f; unsigned u; } v; v.f = f;
  return (v.u + 0x7FFFu + ((v.u >> 16) & 1u)) >> 16;
}
__device__ __forceinline__ float bf2f(unsigned short b) {
  union { unsigned u; float f; } v; v.u = ((unsigned)b) << 16;
  return v.f;
}
__device__ __forceinline__ float2 upk(unsigned u) {  // low ushort -> .x
  union { unsigned u; float f; } a, b;
  a.u = u << 16; b.u = u & 0xFFFF0000u;
  return make_float2(a.f, b.f);
}

// ---------------- CSR build ----------------
__global__ void k_hist(const int* __restrict__ dst, int* __restrict__ cnt) {
  int e = blockIdx.x * blockDim.x + threadIdx.x;
  if (e < NE) atomicAdd(&cnt[dst[e]], 1);
}

__global__ __launch_bounds__(256) void k_psum(const int* __restrict__ cnt,
                                              int* __restrict__ bsum) {
  int t = threadIdx.x;
  int i0 = blockIdx.x * SCHUNK + t * 4;
  int s = 0;
#pragma unroll
  for (int k = 0; k < 4; ++k)
    if (i0 + k < NN) s += cnt[i0 + k];
#pragma unroll
  for (int d = 32; d >= 1; d >>= 1) s += __shfl_down(s, d);
  __shared__ int wsum[4];
  int lane = t & 63, w = t >> 6;
  if (lane == 0) wsum[w] = s;
  __syncthreads();
  if (t == 0) bsum[blockIdx.x] = wsum[0] + wsum[1] + wsum[2] + wsum[3];
}

__global__ void k_bscan(const int* __restrict__ bsum, int* __restrict__ bbase,
                        int* __restrict__ off) {
  int t = threadIdx.x;  // 64 threads
  int v = (t < NSB) ? bsum[t] : 0;
  int incl = v;
#pragma unroll
  for (int d = 1; d < 64; d <<= 1) {
    int u = __shfl_up(incl, d);
    if (t >= d) incl += u;
  }
  if (t < NSB) bbase[t] = incl - v;
  if (t == 63) off[NN] = incl;
}

__global__ __launch_bounds__(256) void k_final(const int* __restrict__ cnt,
                                               const int* __restrict__ bbase,
                                               int* __restrict__ off,
                                               int* __restrict__ cur,
                                               float* __restrict__ dinv) {
  int t = threadIdx.x;
  int lane = t & 63, w = t >> 6;
  int i0 = blockIdx.x * SCHUNK + t * 4;
  int c[4];
  int s = 0;
#pragma unroll
  for (int k = 0; k < 4; ++k) {
    c[k] = (i0 + k < NN) ? cnt[i0 + k] : 0;
    s += c[k];
  }
  int incl = s;
#pragma unroll
  for (int d = 1; d < 64; d <<= 1) {
    int u = __shfl_up(incl, d);
    if (lane >= d) incl += u;
  }
  __shared__ int wsum[4];
  if (lane == 63) wsum[w] = incl;
  __syncthreads();
  int wbase = 0;
  for (int j = 0; j < w; ++j) wbase += wsum[j];
  int run = bbase[blockIdx.x] + wbase + (incl - s);
#pragma unroll
  for (int k = 0; k < 4; ++k) {
    if (i0 + k < NN) {
      off[i0 + k] = run;
      cur[i0 + k] = run;
      dinv[i0 + k] = rsqrtf((float)(c[k] + 1));
      run += c[k];
    }
  }
}

__global__ void k_fill(const int* __restrict__ src, const int* __restrict__ dst,
                       int* __restrict__ cur, int* __restrict__ ssrc) {
  int e = blockIdx.x * blockDim.x + threadIdx.x;
  if (e < NE) {
    int p = atomicAdd(&cur[dst[e]], 1);
    ssrc[p] = src[e];
  }
}

// ---------------- GEMM-1: Hb[n] = bf16( dinv[n] * (X @ W1)[n] ), [NN x 128] ----------------
template <int KD, int ND, int RPI>
__global__ __launch_bounds__(256) void k_gemm_bf(const float* __restrict__ X,
                                                 const float* __restrict__ W,
                                                 const float* __restrict__ dinv,
                                                 unsigned* __restrict__ Hb,  // as uint (2 bf16)
                                                 int ntiles) {
  __shared__ __attribute__((aligned(16))) float Wl[KD * ND];
  __shared__ __attribute__((aligned(16))) float xs[RPI * KD];
  for (int i = threadIdx.x; i < KD * ND / 4; i += 256)
    ((float4*)Wl)[i] = ((const float4*)W)[i];
  const int NQ = ND / 4;
  int q = threadIdx.x % NQ;
  int r = threadIdx.x / NQ;
  for (int tile = blockIdx.x; tile < ntiles; tile += gridDim.x) {
    __syncthreads();
    const float4* Xv = (const float4*)(X + (size_t)tile * RPI * KD);
    for (int i = threadIdx.x; i < RPI * KD / 4; i += 256)
      ((float4*)xs)[i] = Xv[i];
    __syncthreads();
    float4 acc = make_float4(0.f, 0.f, 0.f, 0.f);
    const float* xr = xs + r * KD;
#pragma unroll 8
    for (int k = 0; k < KD; ++k) {
      float xv = xr[k];
      float4 w = ((const float4*)Wl)[k * NQ + q];
      acc.x = fmaf(xv, w.x, acc.x);
      acc.y = fmaf(xv, w.y, acc.y);
      acc.z = fmaf(xv, w.z, acc.z);
      acc.w = fmaf(xv, w.w, acc.w);
    }
    int row = tile * RPI + r;
    float dn = dinv[row];
    unsigned p0 = f2bf(acc.x * dn) | (f2bf(acc.y * dn) << 16);
    unsigned p1 = f2bf(acc.z * dn) | (f2bf(acc.w * dn) << 16);
    ((uint2*)Hb)[(size_t)row * (ND / 4) + q] = make_uint2(p0, p1);
  }
}

// ---------------- fused: layer-1 aggregate + relu + (h2 @ W2) + prescale -> H3 bf16 ----------------
// acc = h1'[n] + sum_s h1'[s]   (h1' prescaled by dinv)
// h2 = relu(dn*acc + b1); h3'[n] = bf16( dn * (h2 @ W2) )
__global__ __launch_bounds__(256) void k_aggf(const unsigned* __restrict__ Hb,
                                              const int* __restrict__ off,
                                              const int* __restrict__ ssrc,
                                              const float* __restrict__ dinv,
                                              const float* __restrict__ b1,
                                              const float* __restrict__ W2,  // [128][64]
                                              unsigned short* __restrict__ H3) {
  __shared__ __attribute__((aligned(16))) float W2l[128 * 64];  // 32 KB
  __shared__ float rowb[4][128];
  for (int i = threadIdx.x; i < 128 * 64 / 4; i += 256)
    ((float4*)W2l)[i] = ((const float4*)W2)[i];
  __syncthreads();  // once; no further block-level syncs
  int lane = threadIdx.x & 63, w = threadIdx.x >> 6;
  int nw = gridDim.x * 4;
  for (int n = blockIdx.x * 4 + w; n < NN; n += nw) {
    float dn = dinv[n];
    int jb = off[n], je = off[n + 1];
    float2 acc = upk(Hb[(size_t)n * 64 + lane]);  // self-loop term
    int j = jb;
    for (; j + 3 < je; j += 4) {
      int s0 = ssrc[j], s1 = ssrc[j + 1], s2 = ssrc[j + 2], s3 = ssrc[j + 3];
      unsigned u0 = Hb[(size_t)s0 * 64 + lane];
      unsigned u1 = Hb[(size_t)s1 * 64 + lane];
      unsigned u2 = Hb[(size_t)s2 * 64 + lane];
      unsigned u3 = Hb[(size_t)s3 * 64 + lane];
      float2 f0 = upk(u0), f1 = upk(u1), f2 = upk(u2), f3 = upk(u3);
      acc.x += f0.x; acc.y += f0.y;
      acc.x += f1.x; acc.y += f1.y;
      acc.x += f2.x; acc.y += f2.y;
      acc.x += f3.x; acc.y += f3.y;
    }
    for (; j < je; ++j) {
      float2 f0 = upk(Hb[(size_t)ssrc[j] * 64 + lane]);
      acc.x += f0.x; acc.y += f0.y;
    }
    float2 b = ((const float2*)b1)[lane];
    float hx = fmaxf(fmaf(dn, acc.x, b.x), 0.f);
    float hy = fmaxf(fmaf(dn, acc.y, b.y), 0.f);
    rowb[w][2 * lane] = hx;
    rowb[w][2 * lane + 1] = hy;  // wave-private; in-wave lgkmcnt ordering suffices
    float o = 0.f;
#pragma unroll 8
    for (int k = 0; k < 128; k += 2) {
      o = fmaf(rowb[w][k], W2l[k * 64 + lane], o);
      o = fmaf(rowb[w][k + 1], W2l[(k + 1) * 64 + lane], o);
    }
    H3[(size_t)n * 64 + lane] = (unsigned short)f2bf(o * dn);
  }
}

// ---------------- layer-2 aggregate: out = relu(dn*(h3'[n] + sum h3'[s]) + b2) ----------------
__global__ __launch_bounds__(256) void k_agg2(const unsigned short* __restrict__ H3,
                                              const int* __restrict__ off,
                                              const int* __restrict__ ssrc,
                                              const float* __restrict__ dinv,
                                              const float* __restrict__ b2,
                                              float* __restrict__ out) {
  int gw = (blockIdx.x * 256 + threadIdx.x) >> 6;
  int lane = threadIdx.x & 63;
  if (gw >= NN) return;
  const int n = gw;
  float dn = dinv[n];
  int jb = off[n], je = off[n + 1];
  float acc = bf2f(H3[(size_t)n * 64 + lane]);
  int j = jb;
  for (; j + 3 < je; j += 4) {
    int s0 = ssrc[j], s1 = ssrc[j + 1], s2 = ssrc[j + 2], s3 = ssrc[j + 3];
    float h0 = bf2f(H3[(size_t)s0 * 64 + lane]);
    float h1 = bf2f(H3[(size_t)s1 * 64 + lane]);
    float h2 = bf2f(H3[(size_t)s2 * 64 + lane]);
    float h3 = bf2f(H3[(size_t)s3 * 64 + lane]);
    acc += h0; acc += h1; acc += h2; acc += h3;
  }
  for (; j < je; ++j) acc += bf2f(H3[(size_t)ssrc[j] * 64 + lane]);
  out[(size_t)n * 64 + lane] = fmaxf(fmaf(dn, acc, b2[lane]), 0.f);
}

extern "C" void kernel_launch(void* const* d_in, const int* in_sizes, int n_in,
                              void* d_out, int out_size, void* d_ws, size_t ws_size,
                              hipStream_t stream) {
  const float* x  = (const float*)d_in[0];
  const int*   ei = (const int*)d_in[1];
  const float* W1 = (const float*)d_in[2];
  const float* b1 = (const float*)d_in[3];
  const float* W2 = (const float*)d_in[4];
  const float* b2 = (const float*)d_in[5];
  const int* esrc = ei;
  const int* edst = ei + NE;

  char* ws = (char*)d_ws;
  int*   cnt  = (int*)(ws + 0);          // 200,000 B
  int*   off  = (int*)(ws + 200704);     // 200,004 B (NN+1)
  int*   cur  = (int*)(ws + 401408);     // 200,000 B
  int*   ssrc = (int*)(ws + 602112);     // 3,200,000 B
  float* dinv = (float*)(ws + 3802112);  // 200,000 B
  int*   bsum = (int*)(ws + 4002112);
  int*   bbase= (int*)(ws + 4003136);
  unsigned*       Hb = (unsigned*)(ws + 4194304);        // bf16 [NN*128] = 12.8 MB
  unsigned short* H3 = (unsigned short*)(ws + 17825792); // bf16 [NN*64]  = 6.4 MB

  hipMemsetAsync(cnt, 0, NN * sizeof(int), stream);
  hipLaunchKernelGGL(k_hist, dim3((NE + 255) / 256), dim3(256), 0, stream, edst, cnt);
  hipLaunchKernelGGL(k_psum, dim3(NSB), dim3(256), 0, stream, cnt, bsum);
  hipLaunchKernelGGL(k_bscan, dim3(1), dim3(64), 0, stream, bsum, bbase, off);
  hipLaunchKernelGGL(k_final, dim3(NSB), dim3(256), 0, stream, cnt, bbase, off, cur, dinv);
  hipLaunchKernelGGL(k_fill, dim3((NE + 255) / 256), dim3(256), 0, stream, esrc, edst, cur, ssrc);

  hipLaunchKernelGGL((k_gemm_bf<128, 128, 8>), dim3(2048), dim3(256), 0, stream,
                     x, W1, dinv, Hb, NN / 8);
  hipLaunchKernelGGL(k_aggf, dim3(2048), dim3(256), 0, stream,
                     Hb, off, ssrc, dinv, b1, W2, H3);
  hipLaunchKernelGGL(k_agg2, dim3((NN * 64 + 255) / 256), dim3(256), 0, stream,
                     H3, off, ssrc, dinv, b2, (float*)d_out);
}

// Round 4
// 238.534 us; speedup vs baseline: 1.7947x; 1.0942x over previous
//
#include <hip/hip_runtime.h>

#define NN 50000
#define NE 800000
#define SCHUNK 1024
#define NSB ((NN + SCHUNK - 1) / SCHUNK)  // 49

// ---------------- bf16 helpers (RNE) ----------------
__device__ __forceinline__ unsigned f2bf(float f) {
  union { float f; unsigned u; } v; v.f = f;
  return (v.u + 0x7FFFu + ((v.u >> 16) & 1u)) >> 16;
}
__device__ __forceinline__ float2 upk(unsigned u) {  // low ushort -> .x
  union { unsigned u; float f; } a, b;
  a.u = u << 16; b.u = u & 0xFFFF0000u;
  return make_float2(a.f, b.f);
}
__device__ __forceinline__ float bf2f(unsigned short b) {
  union { unsigned u; float f; } v; v.u = ((unsigned)b) << 16;
  return v.f;
}
__device__ __forceinline__ void upk8(uint4 v, float* f) {
  float2 a = upk(v.x), b = upk(v.y), c = upk(v.z), d = upk(v.w);
  f[0] = a.x; f[1] = a.y; f[2] = b.x; f[3] = b.y;
  f[4] = c.x; f[5] = c.y; f[6] = d.x; f[7] = d.y;
}
__device__ __forceinline__ unsigned pk2(float a, float b) {
  return f2bf(a) | (f2bf(b) << 16);
}

// ---------------- CSR build ----------------
__global__ void k_hist(const int* __restrict__ dst, int* __restrict__ cnt) {
  int e = blockIdx.x * blockDim.x + threadIdx.x;
  if (e < NE) atomicAdd(&cnt[dst[e]], 1);
}

__global__ __launch_bounds__(256) void k_psum(const int* __restrict__ cnt,
                                              int* __restrict__ bsum) {
  int t = threadIdx.x;
  int i0 = blockIdx.x * SCHUNK + t * 4;
  int s = 0;
#pragma unroll
  for (int k = 0; k < 4; ++k)
    if (i0 + k < NN) s += cnt[i0 + k];
#pragma unroll
  for (int d = 32; d >= 1; d >>= 1) s += __shfl_down(s, d);
  __shared__ int wsum[4];
  int lane = t & 63, w = t >> 6;
  if (lane == 0) wsum[w] = s;
  __syncthreads();
  if (t == 0) bsum[blockIdx.x] = wsum[0] + wsum[1] + wsum[2] + wsum[3];
}

__global__ void k_bscan(const int* __restrict__ bsum, int* __restrict__ bbase,
                        int* __restrict__ off) {
  int t = threadIdx.x;  // 64 threads
  int v = (t < NSB) ? bsum[t] : 0;
  int incl = v;
#pragma unroll
  for (int d = 1; d < 64; d <<= 1) {
    int u = __shfl_up(incl, d);
    if (t >= d) incl += u;
  }
  if (t < NSB) bbase[t] = incl - v;
  if (t == 63) off[NN] = incl;
}

__global__ __launch_bounds__(256) void k_final(const int* __restrict__ cnt,
                                               const int* __restrict__ bbase,
                                               int* __restrict__ off,
                                               int* __restrict__ cur,
                                               float* __restrict__ dinv) {
  int t = threadIdx.x;
  int lane = t & 63, w = t >> 6;
  int i0 = blockIdx.x * SCHUNK + t * 4;
  int c[4];
  int s = 0;
#pragma unroll
  for (int k = 0; k < 4; ++k) {
    c[k] = (i0 + k < NN) ? cnt[i0 + k] : 0;
    s += c[k];
  }
  int incl = s;
#pragma unroll
  for (int d = 1; d < 64; d <<= 1) {
    int u = __shfl_up(incl, d);
    if (lane >= d) incl += u;
  }
  __shared__ int wsum[4];
  if (lane == 63) wsum[w] = incl;
  __syncthreads();
  int wbase = 0;
  for (int j = 0; j < w; ++j) wbase += wsum[j];
  int run = bbase[blockIdx.x] + wbase + (incl - s);
#pragma unroll
  for (int k = 0; k < 4; ++k) {
    if (i0 + k < NN) {
      off[i0 + k] = run;
      cur[i0 + k] = run;
      dinv[i0 + k] = rsqrtf((float)(c[k] + 1));
      run += c[k];
    }
  }
}

__global__ void k_fill(const int* __restrict__ src, const int* __restrict__ dst,
                       int* __restrict__ cur, int* __restrict__ ssrc) {
  int e = blockIdx.x * blockDim.x + threadIdx.x;
  if (e < NE) {
    int p = atomicAdd(&cur[dst[e]], 1);
    ssrc[p] = src[e];
  }
}

// ---------------- GEMM-1: Hb[n] = bf16(dinv[n] * (X @ W1)[n]), X fp32, W1->bf16 LDS ----------------
// 64-row tile per block; thread: o=tid&15 (col-oct of 128), rb=tid>>4 (4 rows each)
__global__ __launch_bounds__(256) void k_gemm1(const float* __restrict__ X,
                                               const float* __restrict__ W1,
                                               const float* __restrict__ dinv,
                                               uint4* __restrict__ Hb4) {
  __shared__ __attribute__((aligned(16))) unsigned W1l[128 * 64];  // bf16[128][128], 32 KB
  __shared__ __attribute__((aligned(16))) unsigned xs[64 * 64];    // bf16[64][128], 16 KB
  const int tid = threadIdx.x;
  const int base = blockIdx.x * 64;
  const float4* W14 = (const float4*)W1;
  const float4* X4 = (const float4*)X;
  uint4* W1l4 = (uint4*)W1l;
  uint4* xs4 = (uint4*)xs;
  // stage W1 as bf16: 2048 uint4
#pragma unroll
  for (int it = 0; it < 8; ++it) {
    int j = tid + 256 * it;
    int krow = j >> 4, c = j & 15;
    float4 f0 = W14[krow * 32 + 2 * c];
    float4 f1 = W14[krow * 32 + 2 * c + 1];
    W1l4[krow * 16 + c] = make_uint4(pk2(f0.x, f0.y), pk2(f0.z, f0.w),
                                     pk2(f1.x, f1.y), pk2(f1.z, f1.w));
  }
  // stage x tile as bf16: 1024 uint4
#pragma unroll
  for (int it = 0; it < 4; ++it) {
    int j = tid + 256 * it;
    int row = j >> 4, c = j & 15;
    int grow = base + row;
    uint4 v = make_uint4(0, 0, 0, 0);
    if (grow < NN) {
      float4 f0 = X4[(size_t)grow * 32 + 2 * c];
      float4 f1 = X4[(size_t)grow * 32 + 2 * c + 1];
      v = make_uint4(pk2(f0.x, f0.y), pk2(f0.z, f0.w), pk2(f1.x, f1.y), pk2(f1.z, f1.w));
    }
    xs4[row * 16 + c] = v;
  }
  __syncthreads();
  const int o = tid & 15, rb = tid >> 4;
  float acc[4][8];
#pragma unroll
  for (int i = 0; i < 4; ++i)
#pragma unroll
    for (int c = 0; c < 8; ++c) acc[i][c] = 0.f;
  for (int kc = 0; kc < 16; ++kc) {
    uint4 xv[4];
    float xf[4][8];
#pragma unroll
    for (int i = 0; i < 4; ++i) {
      xv[i] = xs4[(rb * 4 + i) * 16 + kc];
      upk8(xv[i], xf[i]);
    }
#pragma unroll
    for (int j = 0; j < 8; ++j) {
      uint4 wv = W1l4[(kc * 8 + j) * 16 + o];
      float wf[8];
      upk8(wv, wf);
#pragma unroll
      for (int i = 0; i < 4; ++i) {
        float xk = xf[i][j];
#pragma unroll
        for (int c = 0; c < 8; ++c) acc[i][c] = fmaf(xk, wf[c], acc[i][c]);
      }
    }
  }
#pragma unroll
  for (int i = 0; i < 4; ++i) {
    int grow = base + rb * 4 + i;
    if (grow < NN) {
      float dn = dinv[grow];
      uint4 r;
      r.x = pk2(acc[i][0] * dn, acc[i][1] * dn);
      r.y = pk2(acc[i][2] * dn, acc[i][3] * dn);
      r.z = pk2(acc[i][4] * dn, acc[i][5] * dn);
      r.w = pk2(acc[i][6] * dn, acc[i][7] * dn);
      Hb4[(size_t)grow * 16 + o] = r;
    }
  }
}

// ---------------- agg1: pure gather; h2 = relu(dn*sum + b1) -> bf16 packed ----------------
__global__ __launch_bounds__(256) void k_agg1(const unsigned* __restrict__ Hb,
                                              const int* __restrict__ off,
                                              const int* __restrict__ ssrc,
                                              const float* __restrict__ dinv,
                                              const float* __restrict__ b1,
                                              unsigned* __restrict__ H2) {
  int n = (blockIdx.x * 256 + threadIdx.x) >> 6;
  int lane = threadIdx.x & 63;
  if (n >= NN) return;
  float dn = dinv[n];
  int jb = off[n], je = off[n + 1];
  float2 acc = upk(Hb[(size_t)n * 64 + lane]);  // self-loop (prescaled)
  int j = jb;
  for (; j + 7 < je; j += 8) {
    int s0 = ssrc[j], s1 = ssrc[j + 1], s2 = ssrc[j + 2], s3 = ssrc[j + 3];
    int s4 = ssrc[j + 4], s5 = ssrc[j + 5], s6 = ssrc[j + 6], s7 = ssrc[j + 7];
    unsigned u0 = Hb[(size_t)s0 * 64 + lane], u1 = Hb[(size_t)s1 * 64 + lane];
    unsigned u2 = Hb[(size_t)s2 * 64 + lane], u3 = Hb[(size_t)s3 * 64 + lane];
    unsigned u4 = Hb[(size_t)s4 * 64 + lane], u5 = Hb[(size_t)s5 * 64 + lane];
    unsigned u6 = Hb[(size_t)s6 * 64 + lane], u7 = Hb[(size_t)s7 * 64 + lane];
    float2 f0 = upk(u0), f1 = upk(u1), f2 = upk(u2), f3 = upk(u3);
    float2 f4 = upk(u4), f5 = upk(u5), f6 = upk(u6), f7 = upk(u7);
    acc.x += f0.x + f1.x + f2.x + f3.x + f4.x + f5.x + f6.x + f7.x;
    acc.y += f0.y + f1.y + f2.y + f3.y + f4.y + f5.y + f6.y + f7.y;
  }
  for (; j < je; ++j) {
    float2 f = upk(Hb[(size_t)ssrc[j] * 64 + lane]);
    acc.x += f.x;
    acc.y += f.y;
  }
  float2 b = ((const float2*)b1)[lane];
  float hx = fmaxf(fmaf(dn, acc.x, b.x), 0.f);
  float hy = fmaxf(fmaf(dn, acc.y, b.y), 0.f);
  H2[(size_t)n * 64 + lane] = pk2(hx, hy);
}

// ---------------- GEMM-2: H3[n] = bf16(dinv[n] * (h2 @ W2)[n]), h2 bf16, W2->bf16 LDS ----------------
// 128-row tile; thread: o=tid&7 (col-oct of 64), rb=tid>>3 (4 rows each)
__global__ __launch_bounds__(256) void k_gemm2(const unsigned* __restrict__ H2,
                                               const float* __restrict__ W2,
                                               const float* __restrict__ dinv,
                                               uint4* __restrict__ H34) {
  __shared__ __attribute__((aligned(16))) unsigned W2l[128 * 32];  // bf16[128][64], 16 KB
  __shared__ __attribute__((aligned(16))) unsigned xs[128 * 64];   // bf16[128][128], 32 KB
  const int tid = threadIdx.x;
  const int base = blockIdx.x * 128;
  const float4* W24 = (const float4*)W2;
  const uint4* H2v = (const uint4*)H2;
  uint4* W2l4 = (uint4*)W2l;
  uint4* xs4 = (uint4*)xs;
  // stage W2 as bf16: 1024 uint4
#pragma unroll
  for (int it = 0; it < 4; ++it) {
    int j = tid + 256 * it;
    int krow = j >> 3, c = j & 7;
    float4 f0 = W24[krow * 16 + 2 * c];
    float4 f1 = W24[krow * 16 + 2 * c + 1];
    W2l4[krow * 8 + c] = make_uint4(pk2(f0.x, f0.y), pk2(f0.z, f0.w),
                                    pk2(f1.x, f1.y), pk2(f1.z, f1.w));
  }
  // stage h2 tile (already bf16): 2048 uint4
#pragma unroll
  for (int it = 0; it < 8; ++it) {
    int j = tid + 256 * it;
    int row = j >> 4, c = j & 15;
    int grow = base + row;
    xs4[row * 16 + c] = (grow < NN) ? H2v[(size_t)grow * 16 + c] : make_uint4(0, 0, 0, 0);
  }
  __syncthreads();
  const int o = tid & 7, rb = tid >> 3;
  float acc[4][8];
#pragma unroll
  for (int i = 0; i < 4; ++i)
#pragma unroll
    for (int c = 0; c < 8; ++c) acc[i][c] = 0.f;
  for (int kc = 0; kc < 16; ++kc) {
    uint4 xv[4];
    float xf[4][8];
#pragma unroll
    for (int i = 0; i < 4; ++i) {
      xv[i] = xs4[(rb * 4 + i) * 16 + kc];
      upk8(xv[i], xf[i]);
    }
#pragma unroll
    for (int j = 0; j < 8; ++j) {
      uint4 wv = W2l4[(kc * 8 + j) * 8 + o];
      float wf[8];
      upk8(wv, wf);
#pragma unroll
      for (int i = 0; i < 4; ++i) {
        float xk = xf[i][j];
#pragma unroll
        for (int c = 0; c < 8; ++c) acc[i][c] = fmaf(xk, wf[c], acc[i][c]);
      }
    }
  }
#pragma unroll
  for (int i = 0; i < 4; ++i) {
    int grow = base + rb * 4 + i;
    if (grow < NN) {
      float dn = dinv[grow];
      uint4 r;
      r.x = pk2(acc[i][0] * dn, acc[i][1] * dn);
      r.y = pk2(acc[i][2] * dn, acc[i][3] * dn);
      r.z = pk2(acc[i][4] * dn, acc[i][5] * dn);
      r.w = pk2(acc[i][6] * dn, acc[i][7] * dn);
      H34[(size_t)grow * 8 + o] = r;
    }
  }
}

// ---------------- agg2: out = relu(dn*(h3'[n] + sum h3'[s]) + b2), fp32 out ----------------
__global__ __launch_bounds__(256) void k_agg2(const unsigned short* __restrict__ H3,
                                              const int* __restrict__ off,
                                              const int* __restrict__ ssrc,
                                              const float* __restrict__ dinv,
                                              const float* __restrict__ b2,
                                              float* __restrict__ out) {
  int n = (blockIdx.x * 256 + threadIdx.x) >> 6;
  int lane = threadIdx.x & 63;
  if (n >= NN) return;
  float dn = dinv[n];
  int jb = off[n], je = off[n + 1];
  float acc = bf2f(H3[(size_t)n * 64 + lane]);
  int j = jb;
  for (; j + 7 < je; j += 8) {
    int s0 = ssrc[j], s1 = ssrc[j + 1], s2 = ssrc[j + 2], s3 = ssrc[j + 3];
    int s4 = ssrc[j + 4], s5 = ssrc[j + 5], s6 = ssrc[j + 6], s7 = ssrc[j + 7];
    float h0 = bf2f(H3[(size_t)s0 * 64 + lane]);
    float h1 = bf2f(H3[(size_t)s1 * 64 + lane]);
    float h2 = bf2f(H3[(size_t)s2 * 64 + lane]);
    float h3 = bf2f(H3[(size_t)s3 * 64 + lane]);
    float h4 = bf2f(H3[(size_t)s4 * 64 + lane]);
    float h5 = bf2f(H3[(size_t)s5 * 64 + lane]);
    float h6 = bf2f(H3[(size_t)s6 * 64 + lane]);
    float h7 = bf2f(H3[(size_t)s7 * 64 + lane]);
    acc += h0 + h1 + h2 + h3 + h4 + h5 + h6 + h7;
  }
  for (; j < je; ++j) acc += bf2f(H3[(size_t)ssrc[j] * 64 + lane]);
  out[(size_t)n * 64 + lane] = fmaxf(fmaf(dn, acc, b2[lane]), 0.f);
}

extern "C" void kernel_launch(void* const* d_in, const int* in_sizes, int n_in,
                              void* d_out, int out_size, void* d_ws, size_t ws_size,
                              hipStream_t stream) {
  const float* x  = (const float*)d_in[0];
  const int*   ei = (const int*)d_in[1];
  const float* W1 = (const float*)d_in[2];
  const float* b1 = (const float*)d_in[3];
  const float* W2 = (const float*)d_in[4];
  const float* b2 = (const float*)d_in[5];
  const int* esrc = ei;
  const int* edst = ei + NE;

  char* ws = (char*)d_ws;
  int*   cnt  = (int*)(ws + 0);
  int*   off  = (int*)(ws + 200704);
  int*   cur  = (int*)(ws + 401408);
  int*   ssrc = (int*)(ws + 602112);
  float* dinv = (float*)(ws + 3802112);
  int*   bsum = (int*)(ws + 4002112);
  int*   bbase= (int*)(ws + 4003136);
  unsigned*       Hb = (unsigned*)(ws + 4194304);        // bf16 [NN][128] = 12.8 MB
  unsigned*       H2 = (unsigned*)(ws + 17825792);       // bf16 [NN][128] = 12.8 MB
  unsigned short* H3 = (unsigned short*)(ws + 31457280); // bf16 [NN][64]  = 6.4 MB

  hipMemsetAsync(cnt, 0, NN * sizeof(int), stream);
  hipLaunchKernelGGL(k_hist, dim3((NE + 255) / 256), dim3(256), 0, stream, edst, cnt);
  hipLaunchKernelGGL(k_psum, dim3(NSB), dim3(256), 0, stream, cnt, bsum);
  hipLaunchKernelGGL(k_bscan, dim3(1), dim3(64), 0, stream, bsum, bbase, off);
  hipLaunchKernelGGL(k_final, dim3(NSB), dim3(256), 0, stream, cnt, bbase, off, cur, dinv);
  hipLaunchKernelGGL(k_fill, dim3((NE + 255) / 256), dim3(256), 0, stream, esrc, edst, cur, ssrc);

  hipLaunchKernelGGL(k_gemm1, dim3((NN + 63) / 64), dim3(256), 0, stream,
                     x, W1, dinv, (uint4*)Hb);
  hipLaunchKernelGGL(k_agg1, dim3((NN + 3) / 4), dim3(256), 0, stream,
                     Hb, off, ssrc, dinv, b1, H2);
  hipLaunchKernelGGL(k_gemm2, dim3((NN + 127) / 128), dim3(256), 0, stream,
                     H2, W2, dinv, (uint4*)H3);
  hipLaunchKernelGGL(k_agg2, dim3((NN + 3) / 4), dim3(256), 0, stream,
                     H3, off, ssrc, dinv, b2, (float*)d_out);
}

// Round 5
// 205.802 us; speedup vs baseline: 2.0801x; 1.1590x over previous
//
#include <hip/hip_runtime.h>

#define NN 50000
#define NE 800000
#define SCHUNK 1024
#define NSB ((NN + SCHUNK - 1) / SCHUNK)  // 49
#define NBLK 64            // hist/fill blocks
#define EPB (NE / NBLK)    // 12500 edges per block
#define HALFBINS 25000     // bins per pass
#define HWORDS 12500       // packed u16-pair words per pass (50 KB LDS)

// ---------------- bf16 helpers (RNE) ----------------
__device__ __forceinline__ unsigned f2bf(float f) {
  union { float f; unsigned u; } v; v.f = f;
  return (v.u + 0x7FFFu + ((v.u >> 16) & 1u)) >> 16;
}
__device__ __forceinline__ float2 upk(unsigned u) {  // low ushort -> .x
  union { unsigned u; float f; } a, b;
  a.u = u << 16; b.u = u & 0xFFFF0000u;
  return make_float2(a.f, b.f);
}
__device__ __forceinline__ float bf2f(unsigned short b) {
  union { unsigned u; float f; } v; v.u = ((unsigned)b) << 16;
  return v.f;
}
__device__ __forceinline__ void upk8(uint4 v, float* f) {
  float2 a = upk(v.x), b = upk(v.y), c = upk(v.z), d = upk(v.w);
  f[0] = a.x; f[1] = a.y; f[2] = b.x; f[3] = b.y;
  f[4] = c.x; f[5] = c.y; f[6] = d.x; f[7] = d.y;
}
__device__ __forceinline__ unsigned pk2(float a, float b) {
  return f2bf(a) | (f2bf(b) << 16);
}

// ---------------- CSR build (no global atomics) ----------------
// Per-block packed histogram: partial[b][w] holds counts for bins 2w, 2w+1
__global__ __launch_bounds__(256) void k_hist2(const int* __restrict__ dst,
                                               unsigned* __restrict__ partial) {
  __shared__ unsigned h[HWORDS];  // 50 KB
  const int b = blockIdx.x, tid = threadIdx.x;
  const int e0 = b * EPB;
  unsigned* pb = partial + (size_t)b * 25000;
#pragma unroll
  for (int r = 0; r < 2; ++r) {
    for (int i = tid; i < HWORDS; i += 256) h[i] = 0;
    __syncthreads();
    const int lo = r * HALFBINS;
    for (int k = tid; k < EPB; k += 256) {
      int ld = dst[e0 + k] - lo;
      if ((unsigned)ld < HALFBINS)
        atomicAdd(&h[ld >> 1], 1u << (16 * (ld & 1)));
    }
    __syncthreads();
    for (int i = tid; i < HWORDS; i += 256) pb[r * HWORDS + i] = h[i];
    __syncthreads();
  }
}

// cnt totals + dinv; word w covers bins 2w, 2w+1 (verified: r*25000+2*(w-r*12500)==2w)
__global__ __launch_bounds__(256) void k_merge(const unsigned* __restrict__ partial,
                                               int* __restrict__ cnt,
                                               float* __restrict__ dinv) {
  int w = blockIdx.x * 256 + threadIdx.x;
  if (w >= 25000) return;
  unsigned s0 = 0, s1 = 0;
  for (int b = 0; b < NBLK; ++b) {
    unsigned v = partial[(size_t)b * 25000 + w];
    s0 += v & 0xFFFFu;
    s1 += v >> 16;
  }
  ((int2*)cnt)[w] = make_int2((int)s0, (int)s1);
  ((float2*)dinv)[w] = make_float2(rsqrtf((float)(s0 + 1)), rsqrtf((float)(s1 + 1)));
}

__global__ __launch_bounds__(256) void k_psum(const int* __restrict__ cnt,
                                              int* __restrict__ bsum) {
  int t = threadIdx.x;
  int i0 = blockIdx.x * SCHUNK + t * 4;
  int s = 0;
#pragma unroll
  for (int k = 0; k < 4; ++k)
    if (i0 + k < NN) s += cnt[i0 + k];
#pragma unroll
  for (int d = 32; d >= 1; d >>= 1) s += __shfl_down(s, d);
  __shared__ int wsum[4];
  int lane = t & 63, w = t >> 6;
  if (lane == 0) wsum[w] = s;
  __syncthreads();
  if (t == 0) bsum[blockIdx.x] = wsum[0] + wsum[1] + wsum[2] + wsum[3];
}

__global__ void k_bscan(const int* __restrict__ bsum, int* __restrict__ bbase,
                        int* __restrict__ off) {
  int t = threadIdx.x;  // 64 threads
  int v = (t < NSB) ? bsum[t] : 0;
  int incl = v;
#pragma unroll
  for (int d = 1; d < 64; d <<= 1) {
    int u = __shfl_up(incl, d);
    if (t >= d) incl += u;
  }
  if (t < NSB) bbase[t] = incl - v;
  if (t == 63) off[NN] = incl;
}

__global__ __launch_bounds__(256) void k_final(const int* __restrict__ cnt,
                                               const int* __restrict__ bbase,
                                               int* __restrict__ off) {
  int t = threadIdx.x;
  int lane = t & 63, w = t >> 6;
  int i0 = blockIdx.x * SCHUNK + t * 4;
  int c[4];
  int s = 0;
#pragma unroll
  for (int k = 0; k < 4; ++k) {
    c[k] = (i0 + k < NN) ? cnt[i0 + k] : 0;
    s += c[k];
  }
  int incl = s;
#pragma unroll
  for (int d = 1; d < 64; d <<= 1) {
    int u = __shfl_up(incl, d);
    if (lane >= d) incl += u;
  }
  __shared__ int wsum[4];
  if (lane == 63) wsum[w] = incl;
  __syncthreads();
  int wbase = 0;
  for (int j = 0; j < w; ++j) wbase += wsum[j];
  int run = bbase[blockIdx.x] + wbase + (incl - s);
#pragma unroll
  for (int k = 0; k < 4; ++k) {
    if (i0 + k < NN) {
      off[i0 + k] = run;
      run += c[k];
    }
  }
}

// base[b][bin] = off[bin] + sum_{b'<b} partial_count
__global__ __launch_bounds__(256) void k_base(const unsigned* __restrict__ partial,
                                              const int* __restrict__ off,
                                              int* __restrict__ base) {
  int w = blockIdx.x * 256 + threadIdx.x;
  if (w >= 25000) return;
  int s0 = off[2 * w], s1 = off[2 * w + 1];
  for (int b = 0; b < NBLK; ++b) {
    unsigned v = partial[(size_t)b * 25000 + w];
    ((int2*)(base + (size_t)b * NN))[w] = make_int2(s0, s1);
    s0 += (int)(v & 0xFFFFu);
    s1 += (int)(v >> 16);
  }
}

// ---------------- fused: fill (blocks 0..63) + GEMM-1 (blocks 64..) ----------------
__global__ __launch_bounds__(256) void k_fillgemm(const int* __restrict__ src,
                                                  const int* __restrict__ dst,
                                                  const int* __restrict__ base,
                                                  int* __restrict__ ssrc,
                                                  const float* __restrict__ X,
                                                  const float* __restrict__ W1,
                                                  const float* __restrict__ dinv,
                                                  uint4* __restrict__ Hb4) {
  __shared__ __attribute__((aligned(16))) unsigned smem[12800];  // 51200 B
  const int tid = threadIdx.x;
  if (blockIdx.x < NBLK) {
    // ---- fill role ----
    unsigned* h = smem;
    const int b = blockIdx.x;
    const int e0 = b * EPB;
    const int* bb = base + (size_t)b * NN;
#pragma unroll
    for (int r = 0; r < 2; ++r) {
      for (int i = tid; i < HWORDS; i += 256) h[i] = 0;
      __syncthreads();
      const int lo = r * HALFBINS;
#pragma unroll 4
      for (int k = tid; k < EPB; k += 256) {
        int d = dst[e0 + k];
        int ld = d - lo;
        if ((unsigned)ld < HALFBINS) {
          int sh = 16 * (ld & 1);
          unsigned old = atomicAdd(&h[ld >> 1], 1u << sh);
          int rank = (int)((old >> sh) & 0xFFFFu);
          ssrc[bb[d] + rank] = src[e0 + k];
        }
      }
      __syncthreads();
    }
  } else {
    // ---- GEMM-1 role: 64-row tile ----
    unsigned* W1l = smem;          // bf16[128][128] = 8192 words (32 KB)
    unsigned* xs = smem + 8192;    // bf16[64][128]  = 4096 words (16 KB)
    const int tile = blockIdx.x - NBLK;
    const int bas = tile * 64;
    const float4* W14 = (const float4*)W1;
    const float4* X4 = (const float4*)X;
    uint4* W1l4 = (uint4*)W1l;
    uint4* xs4 = (uint4*)xs;
#pragma unroll
    for (int it = 0; it < 8; ++it) {
      int j = tid + 256 * it;
      int krow = j >> 4, c = j & 15;
      float4 f0 = W14[krow * 32 + 2 * c];
      float4 f1 = W14[krow * 32 + 2 * c + 1];
      W1l4[krow * 16 + c] = make_uint4(pk2(f0.x, f0.y), pk2(f0.z, f0.w),
                                       pk2(f1.x, f1.y), pk2(f1.z, f1.w));
    }
#pragma unroll
    for (int it = 0; it < 4; ++it) {
      int j = tid + 256 * it;
      int row = j >> 4, c = j & 15;
      int grow = bas + row;
      uint4 v = make_uint4(0, 0, 0, 0);
      if (grow < NN) {
        float4 f0 = X4[(size_t)grow * 32 + 2 * c];
        float4 f1 = X4[(size_t)grow * 32 + 2 * c + 1];
        v = make_uint4(pk2(f0.x, f0.y), pk2(f0.z, f0.w), pk2(f1.x, f1.y), pk2(f1.z, f1.w));
      }
      xs4[row * 16 + c] = v;
    }
    __syncthreads();
    const int o = tid & 15, rb = tid >> 4;
    float acc[4][8];
#pragma unroll
    for (int i = 0; i < 4; ++i)
#pragma unroll
      for (int c = 0; c < 8; ++c) acc[i][c] = 0.f;
    for (int kc = 0; kc < 16; ++kc) {
      uint4 xv[4];
      float xf[4][8];
#pragma unroll
      for (int i = 0; i < 4; ++i) {
        xv[i] = xs4[(rb * 4 + i) * 16 + kc];
        upk8(xv[i], xf[i]);
      }
#pragma unroll
      for (int j = 0; j < 8; ++j) {
        uint4 wv = W1l4[(kc * 8 + j) * 16 + o];
        float wf[8];
        upk8(wv, wf);
#pragma unroll
        for (int i = 0; i < 4; ++i) {
          float xk = xf[i][j];
#pragma unroll
          for (int c = 0; c < 8; ++c) acc[i][c] = fmaf(xk, wf[c], acc[i][c]);
        }
      }
    }
#pragma unroll
    for (int i = 0; i < 4; ++i) {
      int grow = bas + rb * 4 + i;
      if (grow < NN) {
        float dn = dinv[grow];
        uint4 rr;
        rr.x = pk2(acc[i][0] * dn, acc[i][1] * dn);
        rr.y = pk2(acc[i][2] * dn, acc[i][3] * dn);
        rr.z = pk2(acc[i][4] * dn, acc[i][5] * dn);
        rr.w = pk2(acc[i][6] * dn, acc[i][7] * dn);
        Hb4[(size_t)grow * 16 + o] = rr;
      }
    }
  }
}

// ---------------- agg1: pure gather; h2 = relu(dn*sum + b1) -> bf16 packed ----------------
__global__ __launch_bounds__(256) void k_agg1(const unsigned* __restrict__ Hb,
                                              const int* __restrict__ off,
                                              const int* __restrict__ ssrc,
                                              const float* __restrict__ dinv,
                                              const float* __restrict__ b1,
                                              unsigned* __restrict__ H2) {
  int n = (blockIdx.x * 256 + threadIdx.x) >> 6;
  int lane = threadIdx.x & 63;
  if (n >= NN) return;
  float dn = dinv[n];
  int jb = off[n], je = off[n + 1];
  float2 acc = upk(Hb[(size_t)n * 64 + lane]);  // self-loop (prescaled)
  int j = jb;
  for (; j + 7 < je; j += 8) {
    int s0 = ssrc[j], s1 = ssrc[j + 1], s2 = ssrc[j + 2], s3 = ssrc[j + 3];
    int s4 = ssrc[j + 4], s5 = ssrc[j + 5], s6 = ssrc[j + 6], s7 = ssrc[j + 7];
    unsigned u0 = Hb[(size_t)s0 * 64 + lane], u1 = Hb[(size_t)s1 * 64 + lane];
    unsigned u2 = Hb[(size_t)s2 * 64 + lane], u3 = Hb[(size_t)s3 * 64 + lane];
    unsigned u4 = Hb[(size_t)s4 * 64 + lane], u5 = Hb[(size_t)s5 * 64 + lane];
    unsigned u6 = Hb[(size_t)s6 * 64 + lane], u7 = Hb[(size_t)s7 * 64 + lane];
    float2 f0 = upk(u0), f1 = upk(u1), f2 = upk(u2), f3 = upk(u3);
    float2 f4 = upk(u4), f5 = upk(u5), f6 = upk(u6), f7 = upk(u7);
    acc.x += f0.x + f1.x + f2.x + f3.x + f4.x + f5.x + f6.x + f7.x;
    acc.y += f0.y + f1.y + f2.y + f3.y + f4.y + f5.y + f6.y + f7.y;
  }
  for (; j < je; ++j) {
    float2 f = upk(Hb[(size_t)ssrc[j] * 64 + lane]);
    acc.x += f.x;
    acc.y += f.y;
  }
  float2 b = ((const float2*)b1)[lane];
  float hx = fmaxf(fmaf(dn, acc.x, b.x), 0.f);
  float hy = fmaxf(fmaf(dn, acc.y, b.y), 0.f);
  H2[(size_t)n * 64 + lane] = pk2(hx, hy);
}

// ---------------- GEMM-2: H3[n] = bf16(dinv[n] * (h2 @ W2)[n]) ----------------
__global__ __launch_bounds__(256) void k_gemm2(const unsigned* __restrict__ H2,
                                               const float* __restrict__ W2,
                                               const float* __restrict__ dinv,
                                               uint4* __restrict__ H34) {
  __shared__ __attribute__((aligned(16))) unsigned W2l[128 * 32];  // 16 KB
  __shared__ __attribute__((aligned(16))) unsigned xs[128 * 64];   // 32 KB
  const int tid = threadIdx.x;
  const int base = blockIdx.x * 128;
  const float4* W24 = (const float4*)W2;
  const uint4* H2v = (const uint4*)H2;
  uint4* W2l4 = (uint4*)W2l;
  uint4* xs4 = (uint4*)xs;
#pragma unroll
  for (int it = 0; it < 4; ++it) {
    int j = tid + 256 * it;
    int krow = j >> 3, c = j & 7;
    float4 f0 = W24[krow * 16 + 2 * c];
    float4 f1 = W24[krow * 16 + 2 * c + 1];
    W2l4[krow * 8 + c] = make_uint4(pk2(f0.x, f0.y), pk2(f0.z, f0.w),
                                    pk2(f1.x, f1.y), pk2(f1.z, f1.w));
  }
#pragma unroll
  for (int it = 0; it < 8; ++it) {
    int j = tid + 256 * it;
    int row = j >> 4, c = j & 15;
    int grow = base + row;
    xs4[row * 16 + c] = (grow < NN) ? H2v[(size_t)grow * 16 + c] : make_uint4(0, 0, 0, 0);
  }
  __syncthreads();
  const int o = tid & 7, rb = tid >> 3;
  float acc[4][8];
#pragma unroll
  for (int i = 0; i < 4; ++i)
#pragma unroll
    for (int c = 0; c < 8; ++c) acc[i][c] = 0.f;
  for (int kc = 0; kc < 16; ++kc) {
    uint4 xv[4];
    float xf[4][8];
#pragma unroll
    for (int i = 0; i < 4; ++i) {
      xv[i] = xs4[(rb * 4 + i) * 16 + kc];
      upk8(xv[i], xf[i]);
    }
#pragma unroll
    for (int j = 0; j < 8; ++j) {
      uint4 wv = W2l4[(kc * 8 + j) * 8 + o];
      float wf[8];
      upk8(wv, wf);
#pragma unroll
      for (int i = 0; i < 4; ++i) {
        float xk = xf[i][j];
#pragma unroll
        for (int c = 0; c < 8; ++c) acc[i][c] = fmaf(xk, wf[c], acc[i][c]);
      }
    }
  }
#pragma unroll
  for (int i = 0; i < 4; ++i) {
    int grow = base + rb * 4 + i;
    if (grow < NN) {
      float dn = dinv[grow];
      uint4 r;
      r.x = pk2(acc[i][0] * dn, acc[i][1] * dn);
      r.y = pk2(acc[i][2] * dn, acc[i][3] * dn);
      r.z = pk2(acc[i][4] * dn, acc[i][5] * dn);
      r.w = pk2(acc[i][6] * dn, acc[i][7] * dn);
      H34[(size_t)grow * 8 + o] = r;
    }
  }
}

// ---------------- agg2: out = relu(dn*(h3'[n] + sum h3'[s]) + b2), fp32 out ----------------
__global__ __launch_bounds__(256) void k_agg2(const unsigned short* __restrict__ H3,
                                              const int* __restrict__ off,
                                              const int* __restrict__ ssrc,
                                              const float* __restrict__ dinv,
                                              const float* __restrict__ b2,
                                              float* __restrict__ out) {
  int n = (blockIdx.x * 256 + threadIdx.x) >> 6;
  int lane = threadIdx.x & 63;
  if (n >= NN) return;
  float dn = dinv[n];
  int jb = off[n], je = off[n + 1];
  float acc = bf2f(H3[(size_t)n * 64 + lane]);
  int j = jb;
  for (; j + 7 < je; j += 8) {
    int s0 = ssrc[j], s1 = ssrc[j + 1], s2 = ssrc[j + 2], s3 = ssrc[j + 3];
    int s4 = ssrc[j + 4], s5 = ssrc[j + 5], s6 = ssrc[j + 6], s7 = ssrc[j + 7];
    float h0 = bf2f(H3[(size_t)s0 * 64 + lane]);
    float h1 = bf2f(H3[(size_t)s1 * 64 + lane]);
    float h2 = bf2f(H3[(size_t)s2 * 64 + lane]);
    float h3 = bf2f(H3[(size_t)s3 * 64 + lane]);
    float h4 = bf2f(H3[(size_t)s4 * 64 + lane]);
    float h5 = bf2f(H3[(size_t)s5 * 64 + lane]);
    float h6 = bf2f(H3[(size_t)s6 * 64 + lane]);
    float h7 = bf2f(H3[(size_t)s7 * 64 + lane]);
    acc += h0 + h1 + h2 + h3 + h4 + h5 + h6 + h7;
  }
  for (; j < je; ++j) acc += bf2f(H3[(size_t)ssrc[j] * 64 + lane]);
  out[(size_t)n * 64 + lane] = fmaxf(fmaf(dn, acc, b2[lane]), 0.f);
}

extern "C" void kernel_launch(void* const* d_in, const int* in_sizes, int n_in,
                              void* d_out, int out_size, void* d_ws, size_t ws_size,
                              hipStream_t stream) {
  const float* x  = (const float*)d_in[0];
  const int*   ei = (const int*)d_in[1];
  const float* W1 = (const float*)d_in[2];
  const float* b1 = (const float*)d_in[3];
  const float* W2 = (const float*)d_in[4];
  const float* b2 = (const float*)d_in[5];
  const int* esrc = ei;
  const int* edst = ei + NE;

  char* ws = (char*)d_ws;
  int*   cnt  = (int*)(ws + 0);                 // 200,000 B
  int*   off  = (int*)(ws + 200704);            // 200,004 B
  float* dinv = (float*)(ws + 401408);          // 200,000 B
  int*   ssrc = (int*)(ws + 602112);            // 3,200,000 B
  int*   bsum = (int*)(ws + 3802112);
  int*   bbase= (int*)(ws + 4003136);
  unsigned*       Hb = (unsigned*)(ws + 4194304);        // bf16 [NN][128] = 12.8 MB, ends 16,994,304
  unsigned*       H2 = (unsigned*)(ws + 17825792);       // bf16 [NN][128] = 12.8 MB, ends 30,625,792
  // partial overlaps H2's slot (dead before agg1 writes H2)
  unsigned*  partial = (unsigned*)(ws + 17825792);       // u32 [64][25000] = 6.4 MB
  // base overlaps H3's slot region (dead before gemm2 writes H3)
  int*          base = (int*)(ws + 30670848);            // u32 [64][50000] = 12.8 MB, ends 43,470,848
  unsigned short* H3 = (unsigned short*)(ws + 30670848); // bf16 [NN][64] = 6.4 MB (after base is dead)

  hipLaunchKernelGGL(k_hist2, dim3(NBLK), dim3(256), 0, stream, edst, partial);
  hipLaunchKernelGGL(k_merge, dim3(98), dim3(256), 0, stream, partial, cnt, dinv);
  hipLaunchKernelGGL(k_psum, dim3(NSB), dim3(256), 0, stream, cnt, bsum);
  hipLaunchKernelGGL(k_bscan, dim3(1), dim3(64), 0, stream, bsum, bbase, off);
  hipLaunchKernelGGL(k_final, dim3(NSB), dim3(256), 0, stream, cnt, bbase, off);
  hipLaunchKernelGGL(k_base, dim3(98), dim3(256), 0, stream, partial, off, base);

  hipLaunchKernelGGL(k_fillgemm, dim3(NBLK + (NN + 63) / 64), dim3(256), 0, stream,
                     esrc, edst, base, ssrc, x, W1, dinv, (uint4*)Hb);
  hipLaunchKernelGGL(k_agg1, dim3((NN + 3) / 4), dim3(256), 0, stream,
                     Hb, off, ssrc, dinv, b1, H2);
  hipLaunchKernelGGL(k_gemm2, dim3((NN + 127) / 128), dim3(256), 0, stream,
                     H2, W2, dinv, (uint4*)H3);
  hipLaunchKernelGGL(k_agg2, dim3((NN + 3) / 4), dim3(256), 0, stream,
                     H3, off, ssrc, dinv, b2, (float*)d_out);
}

// Round 6
// 150.523 us; speedup vs baseline: 2.8440x; 1.3672x over previous
//
#include <hip/hip_runtime.h>

#define NN 50000
#define NE 800000
#define NBUCK 196        // coarse buckets: dst>>8 (256 nodes each; last has 80)
#define BCAP 5120        // per-bucket region capacity (mean 4082, sigma ~64)
#define NPART 256        // partition blocks
#define EPP (NE / NPART) // 3125 edges per partition block

// ---------------- bf16 helpers (RNE) ----------------
__device__ __forceinline__ unsigned f2bf(float f) {
  union { float f; unsigned u; } v; v.f = f;
  return (v.u + 0x7FFFu + ((v.u >> 16) & 1u)) >> 16;
}
__device__ __forceinline__ float2 upk(unsigned u) {  // low ushort -> .x
  union { unsigned u; float f; } a, b;
  a.u = u << 16; b.u = u & 0xFFFF0000u;
  return make_float2(a.f, b.f);
}
__device__ __forceinline__ float bf2f(unsigned short b) {
  union { unsigned u; float f; } v; v.u = ((unsigned)b) << 16;
  return v.f;
}
__device__ __forceinline__ void upk8(uint4 v, float* f) {
  float2 a = upk(v.x), b = upk(v.y), c = upk(v.z), d = upk(v.w);
  f[0] = a.x; f[1] = a.y; f[2] = b.x; f[3] = b.y;
  f[4] = c.x; f[5] = c.y; f[6] = d.x; f[7] = d.y;
}
__device__ __forceinline__ unsigned pk2(float a, float b) {
  return f2bf(a) | (f2bf(b) << 16);
}

// ---------------- Phase A (blocks 0..NPART-1) + GEMM-1 (blocks NPART..) ----------------
// Phase A: partition edges into 196 dst-buckets; all global writes coalesced.
// GEMM-1: Hb[n] = bf16((X @ W1)[n])  (UNscaled; dinv applied in agg1)
__global__ __launch_bounds__(256) void k_partgemm(const int* __restrict__ src,
                                                  const int* __restrict__ dst,
                                                  unsigned* __restrict__ gcur,
                                                  unsigned* __restrict__ part,
                                                  const float* __restrict__ X,
                                                  const float* __restrict__ W1,
                                                  uint4* __restrict__ Hb4) {
  __shared__ __attribute__((aligned(16))) unsigned smem[12288];  // 48 KB
  __shared__ int wsum[4];
  const int tid = threadIdx.x;
  if (blockIdx.x < NPART) {
    // ---- partition role ----
    unsigned* stage = smem;         // [3125] packed (src<<16)|dst
    unsigned* hist  = smem + 3200;  // [196]
    unsigned* curs  = smem + 3400;  // [196]
    unsigned* bbs   = smem + 3600;  // [196] global region base per bucket
    const int e0 = blockIdx.x * EPP;
    for (int i = tid; i < NBUCK; i += 256) hist[i] = 0;
    __syncthreads();
    for (int k = tid; k < EPP; k += 256)
      atomicAdd(&hist[((unsigned)dst[e0 + k]) >> 8], 1u);
    __syncthreads();
    {  // exclusive scan hist -> curs
      int lane = tid & 63, w = tid >> 6;
      unsigned v = (tid < NBUCK) ? hist[tid] : 0;
      unsigned incl = v;
#pragma unroll
      for (int d = 1; d < 64; d <<= 1) {
        unsigned u = __shfl_up(incl, d);
        if (lane >= d) incl += u;
      }
      if (lane == 63) wsum[w] = (int)incl;
      __syncthreads();
      unsigned wpre = 0;
      for (int j = 0; j < w; ++j) wpre += (unsigned)wsum[j];
      if (tid < NBUCK) curs[tid] = wpre + incl - v;
    }
    __syncthreads();
    for (int k = tid; k < EPP; k += 256) {
      int d = dst[e0 + k];
      unsigned slot = atomicAdd(&curs[((unsigned)d) >> 8], 1u);
      stage[slot] = (((unsigned)src[e0 + k]) << 16) | (unsigned)d;
    }
    __syncthreads();
    if (tid < NBUCK) bbs[tid] = atomicAdd(&gcur[tid], hist[tid]);
    __syncthreads();
    // coalesced flush: slot k's bucket recovered from packed dst
    for (int k = tid; k < EPP; k += 256) {
      unsigned v = stage[k];
      unsigned b = (v & 0xFFFFu) >> 8;
      unsigned startb = curs[b] - hist[b];  // curs is now end-of-bucket
      part[b * BCAP + bbs[b] + ((unsigned)k - startb)] = v;
    }
  } else {
    // ---- GEMM-1 role: 64-row tile, XOR-swizzled xs ----
    unsigned* W1l = smem;         // bf16[128][128] = 8192 words (32 KB)
    unsigned* xs = smem + 8192;   // bf16[64][128]  = 4096 words (16 KB)
    const int tile = blockIdx.x - NPART;
    const int bas = tile * 64;
    const float4* W14 = (const float4*)W1;
    const float4* X4 = (const float4*)X;
    uint4* W1l4 = (uint4*)W1l;
    uint4* xs4 = (uint4*)xs;
#pragma unroll
    for (int it = 0; it < 8; ++it) {
      int j = tid + 256 * it;
      int krow = j >> 4, c = j & 15;
      float4 f0 = W14[krow * 32 + 2 * c];
      float4 f1 = W14[krow * 32 + 2 * c + 1];
      W1l4[krow * 16 + c] = make_uint4(pk2(f0.x, f0.y), pk2(f0.z, f0.w),
                                       pk2(f1.x, f1.y), pk2(f1.z, f1.w));
    }
#pragma unroll
    for (int it = 0; it < 4; ++it) {
      int j = tid + 256 * it;
      int row = j >> 4, c = j & 15;
      int grow = bas + row;
      uint4 v = make_uint4(0, 0, 0, 0);
      if (grow < NN) {
        float4 f0 = X4[(size_t)grow * 32 + 2 * c];
        float4 f1 = X4[(size_t)grow * 32 + 2 * c + 1];
        v = make_uint4(pk2(f0.x, f0.y), pk2(f0.z, f0.w), pk2(f1.x, f1.y), pk2(f1.z, f1.w));
      }
      xs4[row * 16 + (c ^ ((row >> 2) & 3))] = v;  // XOR swizzle vs bank conflicts
    }
    __syncthreads();
    const int o = tid & 15, rb = tid >> 4;
    float acc[4][8];
#pragma unroll
    for (int i = 0; i < 4; ++i)
#pragma unroll
      for (int c = 0; c < 8; ++c) acc[i][c] = 0.f;
    for (int kc = 0; kc < 16; ++kc) {
      uint4 xv[4];
      float xf[4][8];
#pragma unroll
      for (int i = 0; i < 4; ++i) {
        xv[i] = xs4[(rb * 4 + i) * 16 + (kc ^ (rb & 3))];
        upk8(xv[i], xf[i]);
      }
#pragma unroll
      for (int j = 0; j < 8; ++j) {
        uint4 wv = W1l4[(kc * 8 + j) * 16 + o];
        float wf[8];
        upk8(wv, wf);
#pragma unroll
        for (int i = 0; i < 4; ++i) {
          float xk = xf[i][j];
#pragma unroll
          for (int c = 0; c < 8; ++c) acc[i][c] = fmaf(xk, wf[c], acc[i][c]);
        }
      }
    }
#pragma unroll
    for (int i = 0; i < 4; ++i) {
      int grow = bas + rb * 4 + i;
      if (grow < NN) {
        uint4 rr;
        rr.x = pk2(acc[i][0], acc[i][1]);
        rr.y = pk2(acc[i][2], acc[i][3]);
        rr.z = pk2(acc[i][4], acc[i][5]);
        rr.w = pk2(acc[i][6], acc[i][7]);
        Hb4[(size_t)grow * 16 + o] = rr;
      }
    }
  }
}

// ---------------- bucket-base scan: bbase[b] = sum_{b'<b} gcur[b'] ----------------
__global__ void k_bksc(const unsigned* __restrict__ gcur, unsigned* __restrict__ bbase) {
  __shared__ int wsum[4];
  int tid = threadIdx.x;  // 256
  int lane = tid & 63, w = tid >> 6;
  unsigned v = (tid < NBUCK) ? gcur[tid] : 0;
  unsigned incl = v;
#pragma unroll
  for (int d = 1; d < 64; d <<= 1) {
    unsigned u = __shfl_up(incl, d);
    if (lane >= d) incl += u;
  }
  if (lane == 63) wsum[w] = (int)incl;
  __syncthreads();
  unsigned wpre = 0;
  for (int j = 0; j < w; ++j) wpre += (unsigned)wsum[j];
  if (tid < NBUCK) bbase[tid] = wpre + incl - v;
}

// ---------------- Phase B: per-bucket bin sort -> off, dinv, ssrc (u16, coalesced) ----------------
__global__ __launch_bounds__(256) void k_bucket(const unsigned* __restrict__ gcur,
                                                const unsigned* __restrict__ bbase,
                                                const unsigned* __restrict__ part,
                                                int* __restrict__ off,
                                                float* __restrict__ dinv,
                                                unsigned short* __restrict__ ssrc) {
  __shared__ unsigned hist[256], curs[256];
  __shared__ unsigned short ssr[BCAP];
  __shared__ int wsum[4];
  const int tid = threadIdx.x, b = blockIdx.x;
  const int nb = (int)gcur[b];
  const int base = (int)bbase[b];
  const unsigned* pp = part + (size_t)b * BCAP;
  hist[tid] = 0;
  __syncthreads();
  for (int k = tid; k < nb; k += 256) atomicAdd(&hist[pp[k] & 255u], 1u);
  __syncthreads();
  unsigned v = hist[tid];
  int lane = tid & 63, w = tid >> 6;
  unsigned incl = v;
#pragma unroll
  for (int d = 1; d < 64; d <<= 1) {
    unsigned u = __shfl_up(incl, d);
    if (lane >= d) incl += u;
  }
  if (lane == 63) wsum[w] = (int)incl;
  __syncthreads();
  unsigned wpre = 0;
  for (int j = 0; j < w; ++j) wpre += (unsigned)wsum[j];
  unsigned excl = wpre + incl - v;
  curs[tid] = excl;
  int node = b * 256 + tid;
  if (node < NN) {
    off[node] = base + (int)excl;
    dinv[node] = rsqrtf((float)(v + 1));
  } else if (node == NN) {
    off[NN] = base + (int)excl;  // == NE
  }
  __syncthreads();
  for (int k = tid; k < nb; k += 256) {
    unsigned vv = pp[k];
    unsigned slot = atomicAdd(&curs[vv & 255u], 1u);
    ssr[slot] = (unsigned short)(vv >> 16);
  }
  __syncthreads();
  for (int k = tid; k < nb; k += 256) ssrc[base + k] = ssr[k];
}

// ---------------- agg1: acc = dn*h[n] + sum ds*h[s]; h2 = relu(dn*acc + b1) -> bf16 ----------------
__global__ __launch_bounds__(256) void k_agg1(const unsigned* __restrict__ Hb,
                                              const int* __restrict__ off,
                                              const unsigned short* __restrict__ ssrc,
                                              const float* __restrict__ dinv,
                                              const float* __restrict__ b1,
                                              unsigned* __restrict__ H2) {
  int n = (blockIdx.x * 256 + threadIdx.x) >> 6;
  int lane = threadIdx.x & 63;
  if (n >= NN) return;
  float dn = dinv[n];
  int jb = off[n], je = off[n + 1];
  float2 self = upk(Hb[(size_t)n * 64 + lane]);
  float2 acc = make_float2(dn * self.x, dn * self.y);
  int j = jb;
  for (; j + 7 < je; j += 8) {
    int s0 = ssrc[j], s1 = ssrc[j + 1], s2 = ssrc[j + 2], s3 = ssrc[j + 3];
    int s4 = ssrc[j + 4], s5 = ssrc[j + 5], s6 = ssrc[j + 6], s7 = ssrc[j + 7];
    float w0 = dinv[s0], w1 = dinv[s1], w2 = dinv[s2], w3 = dinv[s3];
    float w4 = dinv[s4], w5 = dinv[s5], w6 = dinv[s6], w7 = dinv[s7];
    unsigned u0 = Hb[(size_t)s0 * 64 + lane], u1 = Hb[(size_t)s1 * 64 + lane];
    unsigned u2 = Hb[(size_t)s2 * 64 + lane], u3 = Hb[(size_t)s3 * 64 + lane];
    unsigned u4 = Hb[(size_t)s4 * 64 + lane], u5 = Hb[(size_t)s5 * 64 + lane];
    unsigned u6 = Hb[(size_t)s6 * 64 + lane], u7 = Hb[(size_t)s7 * 64 + lane];
    float2 f0 = upk(u0), f1 = upk(u1), f2 = upk(u2), f3 = upk(u3);
    float2 f4 = upk(u4), f5 = upk(u5), f6 = upk(u6), f7 = upk(u7);
    acc.x = fmaf(f0.x, w0, acc.x); acc.y = fmaf(f0.y, w0, acc.y);
    acc.x = fmaf(f1.x, w1, acc.x); acc.y = fmaf(f1.y, w1, acc.y);
    acc.x = fmaf(f2.x, w2, acc.x); acc.y = fmaf(f2.y, w2, acc.y);
    acc.x = fmaf(f3.x, w3, acc.x); acc.y = fmaf(f3.y, w3, acc.y);
    acc.x = fmaf(f4.x, w4, acc.x); acc.y = fmaf(f4.y, w4, acc.y);
    acc.x = fmaf(f5.x, w5, acc.x); acc.y = fmaf(f5.y, w5, acc.y);
    acc.x = fmaf(f6.x, w6, acc.x); acc.y = fmaf(f6.y, w6, acc.y);
    acc.x = fmaf(f7.x, w7, acc.x); acc.y = fmaf(f7.y, w7, acc.y);
  }
  for (; j < je; ++j) {
    int s0 = ssrc[j];
    float w0 = dinv[s0];
    float2 f = upk(Hb[(size_t)s0 * 64 + lane]);
    acc.x = fmaf(f.x, w0, acc.x);
    acc.y = fmaf(f.y, w0, acc.y);
  }
  float2 b = ((const float2*)b1)[lane];
  float hx = fmaxf(fmaf(dn, acc.x, b.x), 0.f);
  float hy = fmaxf(fmaf(dn, acc.y, b.y), 0.f);
  H2[(size_t)n * 64 + lane] = pk2(hx, hy);
}

// ---------------- GEMM-2: H3[n] = bf16(dinv[n] * (h2 @ W2)[n]) ----------------
__global__ __launch_bounds__(256) void k_gemm2(const unsigned* __restrict__ H2,
                                               const float* __restrict__ W2,
                                               const float* __restrict__ dinv,
                                               uint4* __restrict__ H34) {
  __shared__ __attribute__((aligned(16))) unsigned W2l[128 * 32];  // 16 KB
  __shared__ __attribute__((aligned(16))) unsigned xs[128 * 64];   // 32 KB
  const int tid = threadIdx.x;
  const int base = blockIdx.x * 128;
  const float4* W24 = (const float4*)W2;
  const uint4* H2v = (const uint4*)H2;
  uint4* W2l4 = (uint4*)W2l;
  uint4* xs4 = (uint4*)xs;
#pragma unroll
  for (int it = 0; it < 4; ++it) {
    int j = tid + 256 * it;
    int krow = j >> 3, c = j & 7;
    float4 f0 = W24[krow * 16 + 2 * c];
    float4 f1 = W24[krow * 16 + 2 * c + 1];
    W2l4[krow * 8 + c] = make_uint4(pk2(f0.x, f0.y), pk2(f0.z, f0.w),
                                    pk2(f1.x, f1.y), pk2(f1.z, f1.w));
  }
#pragma unroll
  for (int it = 0; it < 8; ++it) {
    int j = tid + 256 * it;
    int row = j >> 4, c = j & 15;
    int grow = base + row;
    uint4 v = (grow < NN) ? H2v[(size_t)grow * 16 + c] : make_uint4(0, 0, 0, 0);
    xs4[row * 16 + (c ^ ((row >> 2) & 3))] = v;  // XOR swizzle
  }
  __syncthreads();
  const int o = tid & 7, rb = tid >> 3;
  float acc[4][8];
#pragma unroll
  for (int i = 0; i < 4; ++i)
#pragma unroll
    for (int c = 0; c < 8; ++c) acc[i][c] = 0.f;
  for (int kc = 0; kc < 16; ++kc) {
    uint4 xv[4];
    float xf[4][8];
#pragma unroll
    for (int i = 0; i < 4; ++i) {
      xv[i] = xs4[(rb * 4 + i) * 16 + (kc ^ (rb & 3))];
      upk8(xv[i], xf[i]);
    }
#pragma unroll
    for (int j = 0; j < 8; ++j) {
      uint4 wv = W2l4[(kc * 8 + j) * 8 + o];
      float wf[8];
      upk8(wv, wf);
#pragma unroll
      for (int i = 0; i < 4; ++i) {
        float xk = xf[i][j];
#pragma unroll
        for (int c = 0; c < 8; ++c) acc[i][c] = fmaf(xk, wf[c], acc[i][c]);
      }
    }
  }
#pragma unroll
  for (int i = 0; i < 4; ++i) {
    int grow = base + rb * 4 + i;
    if (grow < NN) {
      float dn = dinv[grow];
      uint4 r;
      r.x = pk2(acc[i][0] * dn, acc[i][1] * dn);
      r.y = pk2(acc[i][2] * dn, acc[i][3] * dn);
      r.z = pk2(acc[i][4] * dn, acc[i][5] * dn);
      r.w = pk2(acc[i][6] * dn, acc[i][7] * dn);
      H34[(size_t)grow * 8 + o] = r;
    }
  }
}

// ---------------- agg2: out = relu(dn*(h3'[n] + sum h3'[s]) + b2), fp32 out ----------------
__global__ __launch_bounds__(256) void k_agg2(const unsigned short* __restrict__ H3,
                                              const int* __restrict__ off,
                                              const unsigned short* __restrict__ ssrc,
                                              const float* __restrict__ dinv,
                                              const float* __restrict__ b2,
                                              float* __restrict__ out) {
  int n = (blockIdx.x * 256 + threadIdx.x) >> 6;
  int lane = threadIdx.x & 63;
  if (n >= NN) return;
  float dn = dinv[n];
  int jb = off[n], je = off[n + 1];
  float acc = bf2f(H3[(size_t)n * 64 + lane]);
  int j = jb;
  for (; j + 7 < je; j += 8) {
    int s0 = ssrc[j], s1 = ssrc[j + 1], s2 = ssrc[j + 2], s3 = ssrc[j + 3];
    int s4 = ssrc[j + 4], s5 = ssrc[j + 5], s6 = ssrc[j + 6], s7 = ssrc[j + 7];
    float h0 = bf2f(H3[(size_t)s0 * 64 + lane]);
    float h1 = bf2f(H3[(size_t)s1 * 64 + lane]);
    float h2 = bf2f(H3[(size_t)s2 * 64 + lane]);
    float h3 = bf2f(H3[(size_t)s3 * 64 + lane]);
    float h4 = bf2f(H3[(size_t)s4 * 64 + lane]);
    float h5 = bf2f(H3[(size_t)s5 * 64 + lane]);
    float h6 = bf2f(H3[(size_t)s6 * 64 + lane]);
    float h7 = bf2f(H3[(size_t)s7 * 64 + lane]);
    acc += h0 + h1 + h2 + h3 + h4 + h5 + h6 + h7;
  }
  for (; j < je; ++j) acc += bf2f(H3[(size_t)ssrc[j] * 64 + lane]);
  out[(size_t)n * 64 + lane] = fmaxf(fmaf(dn, acc, b2[lane]), 0.f);
}

extern "C" void kernel_launch(void* const* d_in, const int* in_sizes, int n_in,
                              void* d_out, int out_size, void* d_ws, size_t ws_size,
                              hipStream_t stream) {
  const float* x  = (const float*)d_in[0];
  const int*   ei = (const int*)d_in[1];
  const float* W1 = (const float*)d_in[2];
  const float* b1 = (const float*)d_in[3];
  const float* W2 = (const float*)d_in[4];
  const float* b2 = (const float*)d_in[5];
  const int* esrc = ei;
  const int* edst = ei + NE;

  char* ws = (char*)d_ws;
  unsigned* gcur  = (unsigned*)(ws + 0);        // 196*4 = 784 B
  unsigned* bbase = (unsigned*)(ws + 1024);     // 784 B
  int*      off   = (int*)(ws + 2048);          // 200,004 B
  float*    dinv  = (float*)(ws + 204800);      // 200,000 B
  unsigned short* ssrc = (unsigned short*)(ws + 405504);  // 1.6 MB
  unsigned* part  = (unsigned*)(ws + 2097152);  // 196*5120*4 = 4,014,080 B
  unsigned* Hb    = (unsigned*)(ws + 6291456);  // bf16 [NN][128] = 12.8 MB
  unsigned* H2    = (unsigned*)(ws + 19922944); // bf16 [NN][128] = 12.8 MB
  unsigned short* H3 = (unsigned short*)(ws + 33554432);  // bf16 [NN][64] = 6.4 MB

  hipMemsetAsync(gcur, 0, NBUCK * sizeof(unsigned), stream);
  hipLaunchKernelGGL(k_partgemm, dim3(NPART + (NN + 63) / 64), dim3(256), 0, stream,
                     esrc, edst, gcur, part, x, W1, (uint4*)Hb);
  hipLaunchKernelGGL(k_bksc, dim3(1), dim3(256), 0, stream, gcur, bbase);
  hipLaunchKernelGGL(k_bucket, dim3(NBUCK), dim3(256), 0, stream,
                     gcur, bbase, part, off, dinv, ssrc);
  hipLaunchKernelGGL(k_agg1, dim3((NN + 3) / 4), dim3(256), 0, stream,
                     Hb, off, ssrc, dinv, b1, H2);
  hipLaunchKernelGGL(k_gemm2, dim3((NN + 127) / 128), dim3(256), 0, stream,
                     H2, W2, dinv, (uint4*)H3);
  hipLaunchKernelGGL(k_agg2, dim3((NN + 3) / 4), dim3(256), 0, stream,
                     H3, off, ssrc, dinv, b2, (float*)d_out);
}

// Round 9
// 122.729 us; speedup vs baseline: 3.4881x; 1.2265x over previous
//
#include <hip/hip_runtime.h>

#define NN 50000
#define NE 800000
#define NBUCK 196        // coarse buckets: dst>>8
#define BCAP 5120
#define NPART 256
#define EPP (NE / NPART) // 3125

typedef short short8 __attribute__((ext_vector_type(8)));
typedef float f32x4 __attribute__((ext_vector_type(4)));
union U4 { uint4 u; short8 h; };

// ---------------- bf16 helpers (RNE) ----------------
__device__ __forceinline__ unsigned f2bf(float f) {
  union { float f; unsigned u; } v; v.f = f;
  return (v.u + 0x7FFFu + ((v.u >> 16) & 1u)) >> 16;
}
__device__ __forceinline__ float2 upk(unsigned u) {
  union { unsigned u; float f; } a, b;
  a.u = u << 16; b.u = u & 0xFFFF0000u;
  return make_float2(a.f, b.f);
}
__device__ __forceinline__ float bf2f(unsigned short b) {
  union { unsigned u; float f; } v; v.u = ((unsigned)b) << 16;
  return v.f;
}
__device__ __forceinline__ unsigned pk2(float a, float b) {
  return f2bf(a) | (f2bf(b) << 16);
}

// ---------------- prep: W1T/W2T bf16, transposed, k-chunk XOR swizzle baked in ----------------
// WTswz[u16 idx n*128 + (k ^ ((n&7)<<3))] = bf16(W[k][n])
__global__ __launch_bounds__(256) void k_prep(const float* __restrict__ W1,
                                              const float* __restrict__ W2,
                                              unsigned short* __restrict__ W1T,
                                              unsigned short* __restrict__ W2T) {
  int b = blockIdx.x, t = threadIdx.x;
  {  // W1: 16384 elements, 256 per block
    int idx = b * 256 + t;
    int k = idx >> 7, n = idx & 127;
    W1T[(n << 7) + (k ^ ((n & 7) << 3))] = (unsigned short)f2bf(W1[idx]);
  }
  {  // W2: 8192 elements, 128 per block
    if (t < 128) {
      int idx = b * 128 + t;
      int k = idx >> 6, n = idx & 63;
      W2T[(n << 7) + (k ^ ((n & 7) << 3))] = (unsigned short)f2bf(W2[idx]);
    }
  }
}

// ---------------- Phase A partition (blocks 0..255) + MFMA GEMM-1 (blocks 256..) ----------------
__global__ __launch_bounds__(256) void k_partmm1(const int* __restrict__ src,
                                                 const int* __restrict__ dst,
                                                 unsigned* __restrict__ gcur,
                                                 unsigned* __restrict__ part,
                                                 const float* __restrict__ X,
                                                 const unsigned short* __restrict__ W1T,
                                                 unsigned* __restrict__ Hbu) {
  __shared__ __attribute__((aligned(16))) unsigned smem[12288];  // 48 KB
  __shared__ int wsum[4];
  const int tid = threadIdx.x;
  if (blockIdx.x < NPART) {
    // ---- partition role ----
    unsigned* stage = smem;
    unsigned* hist  = smem + 3200;
    unsigned* curs  = smem + 3400;
    unsigned* bbs   = smem + 3600;
    const int e0 = blockIdx.x * EPP;
    for (int i = tid; i < NBUCK; i += 256) hist[i] = 0;
    __syncthreads();
    for (int k = tid; k < EPP; k += 256)
      atomicAdd(&hist[((unsigned)dst[e0 + k]) >> 8], 1u);
    __syncthreads();
    {
      int lane = tid & 63, w = tid >> 6;
      unsigned v = (tid < NBUCK) ? hist[tid] : 0;
      unsigned incl = v;
#pragma unroll
      for (int d = 1; d < 64; d <<= 1) {
        unsigned u = __shfl_up(incl, d);
        if (lane >= d) incl += u;
      }
      if (lane == 63) wsum[w] = (int)incl;
      __syncthreads();
      unsigned wpre = 0;
      for (int j = 0; j < w; ++j) wpre += (unsigned)wsum[j];
      if (tid < NBUCK) curs[tid] = wpre + incl - v;
    }
    __syncthreads();
    for (int k = tid; k < EPP; k += 256) {
      int d = dst[e0 + k];
      unsigned slot = atomicAdd(&curs[((unsigned)d) >> 8], 1u);
      stage[slot] = (((unsigned)src[e0 + k]) << 16) | (unsigned)d;
    }
    __syncthreads();
    if (tid < NBUCK) bbs[tid] = atomicAdd(&gcur[tid], hist[tid]);
    __syncthreads();
    for (int k = tid; k < EPP; k += 256) {
      unsigned v = stage[k];
      unsigned b = (v & 0xFFFFu) >> 8;
      unsigned startb = curs[b] - hist[b];
      part[b * BCAP + bbs[b] + ((unsigned)k - startb)] = v;
    }
  } else {
    // ---- MFMA GEMM-1: 64 rows x 128 cols per block ----
    uint4* w1t4 = (uint4*)smem;          // 2048 uint4 (32 KB)  W1T bf16 [128n][128k] swz
    uint4* xs4  = (uint4*)(smem + 8192); // 1024 uint4 (16 KB)  x tile bf16 [64r][128k] swz
    const int base = (blockIdx.x - NPART) * 64;
    const uint4* W1Tg = (const uint4*)W1T;
    const float4* X4 = (const float4*)X;
#pragma unroll
    for (int it = 0; it < 8; ++it) w1t4[tid + 256 * it] = W1Tg[tid + 256 * it];
#pragma unroll
    for (int it = 0; it < 4; ++it) {
      int j = tid + 256 * it;
      int row = j >> 4, c16 = j & 15;
      int grow = base + row;
      uint4 v = make_uint4(0, 0, 0, 0);
      if (grow < NN) {
        float4 f0 = X4[(size_t)grow * 32 + c16 * 2];
        float4 f1 = X4[(size_t)grow * 32 + c16 * 2 + 1];
        v = make_uint4(pk2(f0.x, f0.y), pk2(f0.z, f0.w), pk2(f1.x, f1.y), pk2(f1.z, f1.w));
      }
      xs4[row * 16 + (c16 ^ (row & 7))] = v;
    }
    __syncthreads();
    const int lane = tid & 63, wv = tid >> 6;
    const int l7 = lane & 7, lg = lane >> 4;
    f32x4 acc[8];
#pragma unroll
    for (int c = 0; c < 8; ++c) acc[c] = (f32x4){0.f, 0.f, 0.f, 0.f};
    const int arow = wv * 16 + (lane & 15);
#pragma unroll
    for (int kk = 0; kk < 4; ++kk) {
      int kcc = kk * 4 + lg;
      U4 a; a.u = xs4[arow * 16 + (kcc ^ l7)];
#pragma unroll
      for (int c = 0; c < 8; ++c) {
        int n = c * 16 + (lane & 15);
        U4 b; b.u = w1t4[n * 16 + (kcc ^ l7)];
        acc[c] = __builtin_amdgcn_mfma_f32_16x16x32_bf16(a.h, b.h, acc[c], 0, 0, 0);
      }
    }
    // epilogue: D col = lane&15, row = (lane>>4)*4 + r  -> pack bf16 pairs via shfl
#pragma unroll
    for (int c = 0; c < 8; ++c) {
#pragma unroll
      for (int r = 0; r < 4; ++r) {
        int grow = base + wv * 16 + lg * 4 + r;
        unsigned mb = f2bf(acc[c][r]);
        unsigned ob = (unsigned)__shfl_xor((int)mb, 1);
        if (((lane & 1) == 0) && grow < NN)
          Hbu[(size_t)grow * 64 + c * 8 + ((lane & 15) >> 1)] = mb | (ob << 16);
      }
    }
  }
}

// ---------------- bucket-base scan ----------------
__global__ void k_bksc(const unsigned* __restrict__ gcur, unsigned* __restrict__ bbase) {
  __shared__ int wsum[4];
  int tid = threadIdx.x;
  int lane = tid & 63, w = tid >> 6;
  unsigned v = (tid < NBUCK) ? gcur[tid] : 0;
  unsigned incl = v;
#pragma unroll
  for (int d = 1; d < 64; d <<= 1) {
    unsigned u = __shfl_up(incl, d);
    if (lane >= d) incl += u;
  }
  if (lane == 63) wsum[w] = (int)incl;
  __syncthreads();
  unsigned wpre = 0;
  for (int j = 0; j < w; ++j) wpre += (unsigned)wsum[j];
  if (tid < NBUCK) bbase[tid] = wpre + incl - v;
}

// ---------------- Phase B: per-bucket bin sort ----------------
__global__ __launch_bounds__(256) void k_bucket(const unsigned* __restrict__ gcur,
                                                const unsigned* __restrict__ bbase,
                                                const unsigned* __restrict__ part,
                                                int* __restrict__ off,
                                                float* __restrict__ dinv,
                                                unsigned short* __restrict__ ssrc) {
  __shared__ unsigned hist[256], curs[256];
  __shared__ unsigned short ssr[BCAP];
  __shared__ int wsum[4];
  const int tid = threadIdx.x, b = blockIdx.x;
  const int nb = (int)gcur[b];
  const int base = (int)bbase[b];
  const unsigned* pp = part + (size_t)b * BCAP;
  hist[tid] = 0;
  __syncthreads();
  for (int k = tid; k < nb; k += 256) atomicAdd(&hist[pp[k] & 255u], 1u);
  __syncthreads();
  unsigned v = hist[tid];
  int lane = tid & 63, w = tid >> 6;
  unsigned incl = v;
#pragma unroll
  for (int d = 1; d < 64; d <<= 1) {
    unsigned u = __shfl_up(incl, d);
    if (lane >= d) incl += u;
  }
  if (lane == 63) wsum[w] = (int)incl;
  __syncthreads();
  unsigned wpre = 0;
  for (int j = 0; j < w; ++j) wpre += (unsigned)wsum[j];
  unsigned excl = wpre + incl - v;
  curs[tid] = excl;
  int node = b * 256 + tid;
  if (node < NN) {
    off[node] = base + (int)excl;
    dinv[node] = rsqrtf((float)(v + 1));
  } else if (node == NN) {
    off[NN] = base + (int)excl;
  }
  __syncthreads();
  for (int k = tid; k < nb; k += 256) {
    unsigned vv = pp[k];
    unsigned slot = atomicAdd(&curs[vv & 255u], 1u);
    ssr[slot] = (unsigned short)(vv >> 16);
  }
  __syncthreads();
  for (int k = tid; k < nb; k += 256) ssrc[base + k] = ssr[k];
}

// ---------------- agg1 ----------------
__global__ __launch_bounds__(256) void k_agg1(const unsigned* __restrict__ Hb,
                                              const int* __restrict__ off,
                                              const unsigned short* __restrict__ ssrc,
                                              const float* __restrict__ dinv,
                                              const float* __restrict__ b1,
                                              unsigned* __restrict__ H2) {
  int n = (blockIdx.x * 256 + threadIdx.x) >> 6;
  int lane = threadIdx.x & 63;
  if (n >= NN) return;
  float dn = dinv[n];
  int jb = off[n], je = off[n + 1];
  float2 self = upk(Hb[(size_t)n * 64 + lane]);
  float2 acc = make_float2(dn * self.x, dn * self.y);
  int j = jb;
  for (; j + 7 < je; j += 8) {
    int s0 = ssrc[j], s1 = ssrc[j + 1], s2 = ssrc[j + 2], s3 = ssrc[j + 3];
    int s4 = ssrc[j + 4], s5 = ssrc[j + 5], s6 = ssrc[j + 6], s7 = ssrc[j + 7];
    float w0 = dinv[s0], w1 = dinv[s1], w2 = dinv[s2], w3 = dinv[s3];
    float w4 = dinv[s4], w5 = dinv[s5], w6 = dinv[s6], w7 = dinv[s7];
    unsigned u0 = Hb[(size_t)s0 * 64 + lane], u1 = Hb[(size_t)s1 * 64 + lane];
    unsigned u2 = Hb[(size_t)s2 * 64 + lane], u3 = Hb[(size_t)s3 * 64 + lane];
    unsigned u4 = Hb[(size_t)s4 * 64 + lane], u5 = Hb[(size_t)s5 * 64 + lane];
    unsigned u6 = Hb[(size_t)s6 * 64 + lane], u7 = Hb[(size_t)s7 * 64 + lane];
    float2 f0 = upk(u0), f1 = upk(u1), f2 = upk(u2), f3 = upk(u3);
    float2 f4 = upk(u4), f5 = upk(u5), f6 = upk(u6), f7 = upk(u7);
    acc.x = fmaf(f0.x, w0, acc.x); acc.y = fmaf(f0.y, w0, acc.y);
    acc.x = fmaf(f1.x, w1, acc.x); acc.y = fmaf(f1.y, w1, acc.y);
    acc.x = fmaf(f2.x, w2, acc.x); acc.y = fmaf(f2.y, w2, acc.y);
    acc.x = fmaf(f3.x, w3, acc.x); acc.y = fmaf(f3.y, w3, acc.y);
    acc.x = fmaf(f4.x, w4, acc.x); acc.y = fmaf(f4.y, w4, acc.y);
    acc.x = fmaf(f5.x, w5, acc.x); acc.y = fmaf(f5.y, w5, acc.y);
    acc.x = fmaf(f6.x, w6, acc.x); acc.y = fmaf(f6.y, w6, acc.y);
    acc.x = fmaf(f7.x, w7, acc.x); acc.y = fmaf(f7.y, w7, acc.y);
  }
  for (; j < je; ++j) {
    int s0 = ssrc[j];
    float w0 = dinv[s0];
    float2 f = upk(Hb[(size_t)s0 * 64 + lane]);
    acc.x = fmaf(f.x, w0, acc.x);
    acc.y = fmaf(f.y, w0, acc.y);
  }
  float2 b = ((const float2*)b1)[lane];
  float hx = fmaxf(fmaf(dn, acc.x, b.x), 0.f);
  float hy = fmaxf(fmaf(dn, acc.y, b.y), 0.f);
  H2[(size_t)n * 64 + lane] = pk2(hx, hy);
}

// ---------------- MFMA GEMM-2: 64 rows x 64 cols per block ----------------
__global__ __launch_bounds__(256) void k_mm2(const unsigned* __restrict__ H2,
                                             const unsigned short* __restrict__ W2T,
                                             const float* __restrict__ dinv,
                                             unsigned* __restrict__ H3u) {
  __shared__ __attribute__((aligned(16))) unsigned smem[8192];  // 32 KB
  uint4* w2t4 = (uint4*)smem;          // 1024 uint4: W2T bf16 [64n][128k] swz
  uint4* xs4  = (uint4*)(smem + 4096); // 1024 uint4: H2 tile bf16 [64r][128k] swz
  const int tid = threadIdx.x;
  const int base = blockIdx.x * 64;
  const uint4* W2Tg = (const uint4*)W2T;
  const uint4* H2v = (const uint4*)H2;
#pragma unroll
  for (int it = 0; it < 4; ++it) w2t4[tid + 256 * it] = W2Tg[tid + 256 * it];
#pragma unroll
  for (int it = 0; it < 4; ++it) {
    int j = tid + 256 * it;
    int row = j >> 4, c16 = j & 15;
    int grow = base + row;
    uint4 v = (grow < NN) ? H2v[(size_t)grow * 16 + c16] : make_uint4(0, 0, 0, 0);
    xs4[row * 16 + (c16 ^ (row & 7))] = v;
  }
  __syncthreads();
  const int lane = tid & 63, wv = tid >> 6;
  const int l7 = lane & 7, lg = lane >> 4;
  f32x4 acc[4];
#pragma unroll
  for (int c = 0; c < 4; ++c) acc[c] = (f32x4){0.f, 0.f, 0.f, 0.f};
  const int arow = wv * 16 + (lane & 15);
#pragma unroll
  for (int kk = 0; kk < 4; ++kk) {
    int kcc = kk * 4 + lg;
    U4 a; a.u = xs4[arow * 16 + (kcc ^ l7)];
#pragma unroll
    for (int c = 0; c < 4; ++c) {
      int n = c * 16 + (lane & 15);
      U4 b; b.u = w2t4[n * 16 + (kcc ^ l7)];
      acc[c] = __builtin_amdgcn_mfma_f32_16x16x32_bf16(a.h, b.h, acc[c], 0, 0, 0);
    }
  }
#pragma unroll
  for (int c = 0; c < 4; ++c) {
#pragma unroll
    for (int r = 0; r < 4; ++r) {
      int grow = base + wv * 16 + lg * 4 + r;
      float dn = (grow < NN) ? dinv[grow] : 0.f;
      unsigned mb = f2bf(acc[c][r] * dn);
      unsigned ob = (unsigned)__shfl_xor((int)mb, 1);
      if (((lane & 1) == 0) && grow < NN)
        H3u[(size_t)grow * 32 + c * 8 + ((lane & 15) >> 1)] = mb | (ob << 16);
    }
  }
}

// ---------------- agg2 ----------------
__global__ __launch_bounds__(256) void k_agg2(const unsigned short* __restrict__ H3,
                                              const int* __restrict__ off,
                                              const unsigned short* __restrict__ ssrc,
                                              const float* __restrict__ dinv,
                                              const float* __restrict__ b2,
                                              float* __restrict__ out) {
  int n = (blockIdx.x * 256 + threadIdx.x) >> 6;
  int lane = threadIdx.x & 63;
  if (n >= NN) return;
  float dn = dinv[n];
  int jb = off[n], je = off[n + 1];
  float acc = bf2f(H3[(size_t)n * 64 + lane]);
  int j = jb;
  for (; j + 7 < je; j += 8) {
    int s0 = ssrc[j], s1 = ssrc[j + 1], s2 = ssrc[j + 2], s3 = ssrc[j + 3];
    int s4 = ssrc[j + 4], s5 = ssrc[j + 5], s6 = ssrc[j + 6], s7 = ssrc[j + 7];
    float h0 = bf2f(H3[(size_t)s0 * 64 + lane]);
    float h1 = bf2f(H3[(size_t)s1 * 64 + lane]);
    float h2 = bf2f(H3[(size_t)s2 * 64 + lane]);
    float h3 = bf2f(H3[(size_t)s3 * 64 + lane]);
    float h4 = bf2f(H3[(size_t)s4 * 64 + lane]);
    float h5 = bf2f(H3[(size_t)s5 * 64 + lane]);
    float h6 = bf2f(H3[(size_t)s6 * 64 + lane]);
    float h7 = bf2f(H3[(size_t)s7 * 64 + lane]);
    acc += h0 + h1 + h2 + h3 + h4 + h5 + h6 + h7;
  }
  for (; j < je; ++j) acc += bf2f(H3[(size_t)ssrc[j] * 64 + lane]);
  out[(size_t)n * 64 + lane] = fmaxf(fmaf(dn, acc, b2[lane]), 0.f);
}

extern "C" void kernel_launch(void* const* d_in, const int* in_sizes, int n_in,
                              void* d_out, int out_size, void* d_ws, size_t ws_size,
                              hipStream_t stream) {
  const float* x  = (const float*)d_in[0];
  const int*   ei = (const int*)d_in[1];
  const float* W1 = (const float*)d_in[2];
  const float* b1 = (const float*)d_in[3];
  const float* W2 = (const float*)d_in[4];
  const float* b2 = (const float*)d_in[5];
  const int* esrc = ei;
  const int* edst = ei + NE;

  char* ws = (char*)d_ws;
  unsigned* gcur  = (unsigned*)(ws + 0);
  unsigned* bbase = (unsigned*)(ws + 1024);
  int*      off   = (int*)(ws + 2048);
  float*    dinv  = (float*)(ws + 204800);
  unsigned short* ssrc = (unsigned short*)(ws + 405504);   // 1.6 MB
  unsigned short* W1T  = (unsigned short*)(ws + 2013184);  // 32 KB
  unsigned short* W2T  = (unsigned short*)(ws + 2045952);  // 16 KB
  unsigned* part  = (unsigned*)(ws + 2097152);             // ~4 MB
  unsigned* Hb    = (unsigned*)(ws + 6291456);             // 12.8 MB
  unsigned* H2    = (unsigned*)(ws + 19922944);            // 12.8 MB
  unsigned short* H3 = (unsigned short*)(ws + 33554432);   // 6.4 MB

  (void)hipMemsetAsync(gcur, 0, NBUCK * sizeof(unsigned), stream);
  hipLaunchKernelGGL(k_prep, dim3(64), dim3(256), 0, stream, W1, W2, W1T, W2T);
  hipLaunchKernelGGL(k_partmm1, dim3(NPART + (NN + 63) / 64), dim3(256), 0, stream,
                     esrc, edst, gcur, part, x, W1T, Hb);
  hipLaunchKernelGGL(k_bksc, dim3(1), dim3(256), 0, stream, gcur, bbase);
  hipLaunchKernelGGL(k_bucket, dim3(NBUCK), dim3(256), 0, stream,
                     gcur, bbase, part, off, dinv, ssrc);
  hipLaunchKernelGGL(k_agg1, dim3((NN + 3) / 4), dim3(256), 0, stream,
                     Hb, off, ssrc, dinv, b1, H2);
  hipLaunchKernelGGL(k_mm2, dim3((NN + 63) / 64), dim3(256), 0, stream,
                     H2, W2T, dinv, (unsigned*)H3);
  hipLaunchKernelGGL(k_agg2, dim3((NN + 3) / 4), dim3(256), 0, stream,
                     H3, off, ssrc, dinv, b2, (float*)d_out);
}

// Round 10
// 120.625 us; speedup vs baseline: 3.5490x; 1.0174x over previous
//
#include <hip/hip_runtime.h>

#define NN 50000
#define NE 800000
#define NBUCK 196        // coarse buckets: dst>>8
#define BCAP 5120
#define NPART 256
#define EPP (NE / NPART) // 3125

typedef short short8 __attribute__((ext_vector_type(8)));
typedef float f32x4 __attribute__((ext_vector_type(4)));
union U4 { uint4 u; short8 h; };

// ---------------- bf16 helpers (RNE) ----------------
__device__ __forceinline__ unsigned f2bf(float f) {
  union { float f; unsigned u; } v; v.f = f;
  return (v.u + 0x7FFFu + ((v.u >> 16) & 1u)) >> 16;
}
__device__ __forceinline__ float2 upk(unsigned u) {
  union { unsigned u; float f; } a, b;
  a.u = u << 16; b.u = u & 0xFFFF0000u;
  return make_float2(a.f, b.f);
}
__device__ __forceinline__ float bf2f(unsigned short b) {
  union { unsigned u; float f; } v; v.u = ((unsigned)b) << 16;
  return v.f;
}
__device__ __forceinline__ unsigned pk2(float a, float b) {
  return f2bf(a) | (f2bf(b) << 16);
}

// ---------------- prep: W1T/W2T bf16 transposed+swizzled; also zeros gcur ----------------
// WTswz[u16 idx n*128 + (k ^ ((n&7)<<3))] = bf16(W[k][n])
__global__ __launch_bounds__(256) void k_prep(const float* __restrict__ W1,
                                              const float* __restrict__ W2,
                                              unsigned short* __restrict__ W1T,
                                              unsigned short* __restrict__ W2T,
                                              unsigned* __restrict__ gcur) {
  int b = blockIdx.x, t = threadIdx.x;
  if (b == 0 && t < NBUCK) gcur[t] = 0;  // replaces hipMemsetAsync (41 us in-graph!)
  {  // W1: 16384 elements, 256 per block
    int idx = b * 256 + t;
    int k = idx >> 7, n = idx & 127;
    W1T[(n << 7) + (k ^ ((n & 7) << 3))] = (unsigned short)f2bf(W1[idx]);
  }
  {  // W2: 8192 elements, 128 per block
    if (t < 128) {
      int idx = b * 128 + t;
      int k = idx >> 6, n = idx & 63;
      W2T[(n << 7) + (k ^ ((n & 7) << 3))] = (unsigned short)f2bf(W2[idx]);
    }
  }
}

// ---------------- Phase A partition (blocks 0..255) + MFMA GEMM-1 (blocks 256..) ----------------
__global__ __launch_bounds__(256) void k_partmm1(const int* __restrict__ src,
                                                 const int* __restrict__ dst,
                                                 unsigned* __restrict__ gcur,
                                                 unsigned* __restrict__ part,
                                                 const float* __restrict__ X,
                                                 const unsigned short* __restrict__ W1T,
                                                 unsigned* __restrict__ Hbu) {
  __shared__ __attribute__((aligned(16))) unsigned smem[12288];  // 48 KB
  __shared__ int wsum[4];
  const int tid = threadIdx.x;
  if (blockIdx.x < NPART) {
    // ---- partition role ----
    unsigned* stage = smem;
    unsigned* hist  = smem + 3200;
    unsigned* curs  = smem + 3400;
    unsigned* bbs   = smem + 3600;
    const int e0 = blockIdx.x * EPP;
    for (int i = tid; i < NBUCK; i += 256) hist[i] = 0;
    __syncthreads();
    for (int k = tid; k < EPP; k += 256)
      atomicAdd(&hist[((unsigned)dst[e0 + k]) >> 8], 1u);
    __syncthreads();
    {
      int lane = tid & 63, w = tid >> 6;
      unsigned v = (tid < NBUCK) ? hist[tid] : 0;
      unsigned incl = v;
#pragma unroll
      for (int d = 1; d < 64; d <<= 1) {
        unsigned u = __shfl_up(incl, d);
        if (lane >= d) incl += u;
      }
      if (lane == 63) wsum[w] = (int)incl;
      __syncthreads();
      unsigned wpre = 0;
      for (int j = 0; j < w; ++j) wpre += (unsigned)wsum[j];
      if (tid < NBUCK) curs[tid] = wpre + incl - v;
    }
    __syncthreads();
    for (int k = tid; k < EPP; k += 256) {
      int d = dst[e0 + k];
      unsigned slot = atomicAdd(&curs[((unsigned)d) >> 8], 1u);
      stage[slot] = (((unsigned)src[e0 + k]) << 16) | (unsigned)d;
    }
    __syncthreads();
    if (tid < NBUCK) bbs[tid] = atomicAdd(&gcur[tid], hist[tid]);
    __syncthreads();
    for (int k = tid; k < EPP; k += 256) {
      unsigned v = stage[k];
      unsigned b = (v & 0xFFFFu) >> 8;
      unsigned startb = curs[b] - hist[b];
      part[b * BCAP + bbs[b] + ((unsigned)k - startb)] = v;
    }
  } else {
    // ---- MFMA GEMM-1: 64 rows x 128 cols per block ----
    uint4* w1t4 = (uint4*)smem;          // 2048 uint4 (32 KB)  W1T bf16 [128n][128k] swz
    uint4* xs4  = (uint4*)(smem + 8192); // 1024 uint4 (16 KB)  x tile bf16 [64r][128k] swz
    const int base = (blockIdx.x - NPART) * 64;
    const uint4* W1Tg = (const uint4*)W1T;
    const float4* X4 = (const float4*)X;
#pragma unroll
    for (int it = 0; it < 8; ++it) w1t4[tid + 256 * it] = W1Tg[tid + 256 * it];
#pragma unroll
    for (int it = 0; it < 4; ++it) {
      int j = tid + 256 * it;
      int row = j >> 4, c16 = j & 15;
      int grow = base + row;
      uint4 v = make_uint4(0, 0, 0, 0);
      if (grow < NN) {
        float4 f0 = X4[(size_t)grow * 32 + c16 * 2];
        float4 f1 = X4[(size_t)grow * 32 + c16 * 2 + 1];
        v = make_uint4(pk2(f0.x, f0.y), pk2(f0.z, f0.w), pk2(f1.x, f1.y), pk2(f1.z, f1.w));
      }
      xs4[row * 16 + (c16 ^ (row & 7))] = v;
    }
    __syncthreads();
    const int lane = tid & 63, wv = tid >> 6;
    const int l7 = lane & 7, lg = lane >> 4;
    f32x4 acc[8];
#pragma unroll
    for (int c = 0; c < 8; ++c) acc[c] = (f32x4){0.f, 0.f, 0.f, 0.f};
    const int arow = wv * 16 + (lane & 15);
#pragma unroll
    for (int kk = 0; kk < 4; ++kk) {
      int kcc = kk * 4 + lg;
      U4 a; a.u = xs4[arow * 16 + (kcc ^ l7)];
#pragma unroll
      for (int c = 0; c < 8; ++c) {
        int n = c * 16 + (lane & 15);
        U4 b; b.u = w1t4[n * 16 + (kcc ^ l7)];
        acc[c] = __builtin_amdgcn_mfma_f32_16x16x32_bf16(a.h, b.h, acc[c], 0, 0, 0);
      }
    }
    // epilogue: D col = lane&15, row = (lane>>4)*4 + r  -> pack bf16 pairs via shfl
#pragma unroll
    for (int c = 0; c < 8; ++c) {
#pragma unroll
      for (int r = 0; r < 4; ++r) {
        int grow = base + wv * 16 + lg * 4 + r;
        unsigned mb = f2bf(acc[c][r]);
        unsigned ob = (unsigned)__shfl_xor((int)mb, 1);
        if (((lane & 1) == 0) && grow < NN)
          Hbu[(size_t)grow * 64 + c * 8 + ((lane & 15) >> 1)] = mb | (ob << 16);
      }
    }
  }
}

// ---------------- bucket-base scan ----------------
__global__ void k_bksc(const unsigned* __restrict__ gcur, unsigned* __restrict__ bbase) {
  __shared__ int wsum[4];
  int tid = threadIdx.x;
  int lane = tid & 63, w = tid >> 6;
  unsigned v = (tid < NBUCK) ? gcur[tid] : 0;
  unsigned incl = v;
#pragma unroll
  for (int d = 1; d < 64; d <<= 1) {
    unsigned u = __shfl_up(incl, d);
    if (lane >= d) incl += u;
  }
  if (lane == 63) wsum[w] = (int)incl;
  __syncthreads();
  unsigned wpre = 0;
  for (int j = 0; j < w; ++j) wpre += (unsigned)wsum[j];
  if (tid < NBUCK) bbase[tid] = wpre + incl - v;
}

// ---------------- Phase B: per-bucket bin sort ----------------
__global__ __launch_bounds__(256) void k_bucket(const unsigned* __restrict__ gcur,
                                                const unsigned* __restrict__ bbase,
                                                const unsigned* __restrict__ part,
                                                int* __restrict__ off,
                                                float* __restrict__ dinv,
                                                unsigned short* __restrict__ ssrc) {
  __shared__ unsigned hist[256], curs[256];
  __shared__ unsigned short ssr[BCAP];
  __shared__ int wsum[4];
  const int tid = threadIdx.x, b = blockIdx.x;
  const int nb = (int)gcur[b];
  const int base = (int)bbase[b];
  const unsigned* pp = part + (size_t)b * BCAP;
  hist[tid] = 0;
  __syncthreads();
  for (int k = tid; k < nb; k += 256) atomicAdd(&hist[pp[k] & 255u], 1u);
  __syncthreads();
  unsigned v = hist[tid];
  int lane = tid & 63, w = tid >> 6;
  unsigned incl = v;
#pragma unroll
  for (int d = 1; d < 64; d <<= 1) {
    unsigned u = __shfl_up(incl, d);
    if (lane >= d) incl += u;
  }
  if (lane == 63) wsum[w] = (int)incl;
  __syncthreads();
  unsigned wpre = 0;
  for (int j = 0; j < w; ++j) wpre += (unsigned)wsum[j];
  unsigned excl = wpre + incl - v;
  curs[tid] = excl;
  int node = b * 256 + tid;
  if (node < NN) {
    off[node] = base + (int)excl;
    dinv[node] = rsqrtf((float)(v + 1));
  } else if (node == NN) {
    off[NN] = base + (int)excl;
  }
  __syncthreads();
  for (int k = tid; k < nb; k += 256) {
    unsigned vv = pp[k];
    unsigned slot = atomicAdd(&curs[vv & 255u], 1u);
    ssr[slot] = (unsigned short)(vv >> 16);
  }
  __syncthreads();
  for (int k = tid; k < nb; k += 256) ssrc[base + k] = ssr[k];
}

// ---------------- agg1 ----------------
__global__ __launch_bounds__(256) void k_agg1(const unsigned* __restrict__ Hb,
                                              const int* __restrict__ off,
                                              const unsigned short* __restrict__ ssrc,
                                              const float* __restrict__ dinv,
                                              const float* __restrict__ b1,
                                              unsigned* __restrict__ H2) {
  int n = (blockIdx.x * 256 + threadIdx.x) >> 6;
  int lane = threadIdx.x & 63;
  if (n >= NN) return;
  float dn = dinv[n];
  int jb = off[n], je = off[n + 1];
  float2 self = upk(Hb[(size_t)n * 64 + lane]);
  float2 acc = make_float2(dn * self.x, dn * self.y);
  int j = jb;
  for (; j + 7 < je; j += 8) {
    int s0 = ssrc[j], s1 = ssrc[j + 1], s2 = ssrc[j + 2], s3 = ssrc[j + 3];
    int s4 = ssrc[j + 4], s5 = ssrc[j + 5], s6 = ssrc[j + 6], s7 = ssrc[j + 7];
    float w0 = dinv[s0], w1 = dinv[s1], w2 = dinv[s2], w3 = dinv[s3];
    float w4 = dinv[s4], w5 = dinv[s5], w6 = dinv[s6], w7 = dinv[s7];
    unsigned u0 = Hb[(size_t)s0 * 64 + lane], u1 = Hb[(size_t)s1 * 64 + lane];
    unsigned u2 = Hb[(size_t)s2 * 64 + lane], u3 = Hb[(size_t)s3 * 64 + lane];
    unsigned u4 = Hb[(size_t)s4 * 64 + lane], u5 = Hb[(size_t)s5 * 64 + lane];
    unsigned u6 = Hb[(size_t)s6 * 64 + lane], u7 = Hb[(size_t)s7 * 64 + lane];
    float2 f0 = upk(u0), f1 = upk(u1), f2 = upk(u2), f3 = upk(u3);
    float2 f4 = upk(u4), f5 = upk(u5), f6 = upk(u6), f7 = upk(u7);
    acc.x = fmaf(f0.x, w0, acc.x); acc.y = fmaf(f0.y, w0, acc.y);
    acc.x = fmaf(f1.x, w1, acc.x); acc.y = fmaf(f1.y, w1, acc.y);
    acc.x = fmaf(f2.x, w2, acc.x); acc.y = fmaf(f2.y, w2, acc.y);
    acc.x = fmaf(f3.x, w3, acc.x); acc.y = fmaf(f3.y, w3, acc.y);
    acc.x = fmaf(f4.x, w4, acc.x); acc.y = fmaf(f4.y, w4, acc.y);
    acc.x = fmaf(f5.x, w5, acc.x); acc.y = fmaf(f5.y, w5, acc.y);
    acc.x = fmaf(f6.x, w6, acc.x); acc.y = fmaf(f6.y, w6, acc.y);
    acc.x = fmaf(f7.x, w7, acc.x); acc.y = fmaf(f7.y, w7, acc.y);
  }
  for (; j < je; ++j) {
    int s0 = ssrc[j];
    float w0 = dinv[s0];
    float2 f = upk(Hb[(size_t)s0 * 64 + lane]);
    acc.x = fmaf(f.x, w0, acc.x);
    acc.y = fmaf(f.y, w0, acc.y);
  }
  float2 b = ((const float2*)b1)[lane];
  float hx = fmaxf(fmaf(dn, acc.x, b.x), 0.f);
  float hy = fmaxf(fmaf(dn, acc.y, b.y), 0.f);
  H2[(size_t)n * 64 + lane] = pk2(hx, hy);
}

// ---------------- MFMA GEMM-2: 64 rows x 64 cols per block ----------------
__global__ __launch_bounds__(256) void k_mm2(const unsigned* __restrict__ H2,
                                             const unsigned short* __restrict__ W2T,
                                             const float* __restrict__ dinv,
                                             unsigned* __restrict__ H3u) {
  __shared__ __attribute__((aligned(16))) unsigned smem[8192];  // 32 KB
  uint4* w2t4 = (uint4*)smem;          // 1024 uint4: W2T bf16 [64n][128k] swz
  uint4* xs4  = (uint4*)(smem + 4096); // 1024 uint4: H2 tile bf16 [64r][128k] swz
  const int tid = threadIdx.x;
  const int base = blockIdx.x * 64;
  const uint4* W2Tg = (const uint4*)W2T;
  const uint4* H2v = (const uint4*)H2;
#pragma unroll
  for (int it = 0; it < 4; ++it) w2t4[tid + 256 * it] = W2Tg[tid + 256 * it];
#pragma unroll
  for (int it = 0; it < 4; ++it) {
    int j = tid + 256 * it;
    int row = j >> 4, c16 = j & 15;
    int grow = base + row;
    uint4 v = (grow < NN) ? H2v[(size_t)grow * 16 + c16] : make_uint4(0, 0, 0, 0);
    xs4[row * 16 + (c16 ^ (row & 7))] = v;
  }
  __syncthreads();
  const int lane = tid & 63, wv = tid >> 6;
  const int l7 = lane & 7, lg = lane >> 4;
  f32x4 acc[4];
#pragma unroll
  for (int c = 0; c < 4; ++c) acc[c] = (f32x4){0.f, 0.f, 0.f, 0.f};
  const int arow = wv * 16 + (lane & 15);
#pragma unroll
  for (int kk = 0; kk < 4; ++kk) {
    int kcc = kk * 4 + lg;
    U4 a; a.u = xs4[arow * 16 + (kcc ^ l7)];
#pragma unroll
    for (int c = 0; c < 4; ++c) {
      int n = c * 16 + (lane & 15);
      U4 b; b.u = w2t4[n * 16 + (kcc ^ l7)];
      acc[c] = __builtin_amdgcn_mfma_f32_16x16x32_bf16(a.h, b.h, acc[c], 0, 0, 0);
    }
  }
#pragma unroll
  for (int c = 0; c < 4; ++c) {
#pragma unroll
    for (int r = 0; r < 4; ++r) {
      int grow = base + wv * 16 + lg * 4 + r;
      float dn = (grow < NN) ? dinv[grow] : 0.f;
      unsigned mb = f2bf(acc[c][r] * dn);
      unsigned ob = (unsigned)__shfl_xor((int)mb, 1);
      if (((lane & 1) == 0) && grow < NN)
        H3u[(size_t)grow * 32 + c * 8 + ((lane & 15) >> 1)] = mb | (ob << 16);
    }
  }
}

// ---------------- agg2 ----------------
__global__ __launch_bounds__(256) void k_agg2(const unsigned short* __restrict__ H3,
                                              const int* __restrict__ off,
                                              const unsigned short* __restrict__ ssrc,
                                              const float* __restrict__ dinv,
                                              const float* __restrict__ b2,
                                              float* __restrict__ out) {
  int n = (blockIdx.x * 256 + threadIdx.x) >> 6;
  int lane = threadIdx.x & 63;
  if (n >= NN) return;
  float dn = dinv[n];
  int jb = off[n], je = off[n + 1];
  float acc = bf2f(H3[(size_t)n * 64 + lane]);
  int j = jb;
  for (; j + 7 < je; j += 8) {
    int s0 = ssrc[j], s1 = ssrc[j + 1], s2 = ssrc[j + 2], s3 = ssrc[j + 3];
    int s4 = ssrc[j + 4], s5 = ssrc[j + 5], s6 = ssrc[j + 6], s7 = ssrc[j + 7];
    float h0 = bf2f(H3[(size_t)s0 * 64 + lane]);
    float h1 = bf2f(H3[(size_t)s1 * 64 + lane]);
    float h2 = bf2f(H3[(size_t)s2 * 64 + lane]);
    float h3 = bf2f(H3[(size_t)s3 * 64 + lane]);
    float h4 = bf2f(H3[(size_t)s4 * 64 + lane]);
    float h5 = bf2f(H3[(size_t)s5 * 64 + lane]);
    float h6 = bf2f(H3[(size_t)s6 * 64 + lane]);
    float h7 = bf2f(H3[(size_t)s7 * 64 + lane]);
    acc += h0 + h1 + h2 + h3 + h4 + h5 + h6 + h7;
  }
  for (; j < je; ++j) acc += bf2f(H3[(size_t)ssrc[j] * 64 + lane]);
  out[(size_t)n * 64 + lane] = fmaxf(fmaf(dn, acc, b2[lane]), 0.f);
}

extern "C" void kernel_launch(void* const* d_in, const int* in_sizes, int n_in,
                              void* d_out, int out_size, void* d_ws, size_t ws_size,
                              hipStream_t stream) {
  const float* x  = (const float*)d_in[0];
  const int*   ei = (const int*)d_in[1];
  const float* W1 = (const float*)d_in[2];
  const float* b1 = (const float*)d_in[3];
  const float* W2 = (const float*)d_in[4];
  const float* b2 = (const float*)d_in[5];
  const int* esrc = ei;
  const int* edst = ei + NE;

  char* ws = (char*)d_ws;
  unsigned* gcur  = (unsigned*)(ws + 0);
  unsigned* bbase = (unsigned*)(ws + 1024);
  int*      off   = (int*)(ws + 2048);
  float*    dinv  = (float*)(ws + 204800);
  unsigned short* ssrc = (unsigned short*)(ws + 405504);   // 1.6 MB
  unsigned short* W1T  = (unsigned short*)(ws + 2013184);  // 32 KB
  unsigned short* W2T  = (unsigned short*)(ws + 2045952);  // 16 KB
  unsigned* part  = (unsigned*)(ws + 2097152);             // ~4 MB
  unsigned* Hb    = (unsigned*)(ws + 6291456);             // 12.8 MB
  unsigned* H2    = (unsigned*)(ws + 19922944);            // 12.8 MB
  unsigned short* H3 = (unsigned short*)(ws + 33554432);   // 6.4 MB

  hipLaunchKernelGGL(k_prep, dim3(64), dim3(256), 0, stream, W1, W2, W1T, W2T, gcur);
  hipLaunchKernelGGL(k_partmm1, dim3(NPART + (NN + 63) / 64), dim3(256), 0, stream,
                     esrc, edst, gcur, part, x, W1T, Hb);
  hipLaunchKernelGGL(k_bksc, dim3(1), dim3(256), 0, stream, gcur, bbase);
  hipLaunchKernelGGL(k_bucket, dim3(NBUCK), dim3(256), 0, stream,
                     gcur, bbase, part, off, dinv, ssrc);
  hipLaunchKernelGGL(k_agg1, dim3((NN + 3) / 4), dim3(256), 0, stream,
                     Hb, off, ssrc, dinv, b1, H2);
  hipLaunchKernelGGL(k_mm2, dim3((NN + 63) / 64), dim3(256), 0, stream,
                     H2, W2T, dinv, (unsigned*)H3);
  hipLaunchKernelGGL(k_agg2, dim3((NN + 3) / 4), dim3(256), 0, stream,
                     H3, off, ssrc, dinv, b2, (float*)d_out);
}